// Round 18
// baseline (139.977 us; speedup 1.0000x reference)
//
#include <hip/hip_runtime.h>

typedef unsigned short u16;
typedef unsigned int u32;
typedef __bf16 bf16x8 __attribute__((ext_vector_type(8)));
typedef float f32x4 __attribute__((ext_vector_type(4)));
typedef float f32x16 __attribute__((ext_vector_type(16)));
typedef unsigned short u16x4 __attribute__((ext_vector_type(4)));
typedef unsigned short u16x8 __attribute__((ext_vector_type(8)));
typedef unsigned int u32x2 __attribute__((ext_vector_type(2)));
typedef unsigned int u32x4 __attribute__((ext_vector_type(4)));

#define BB 2
#define SS 2048
#define EE 1024
#define HH 16
#define DD 64

#define QSCALE_F 0.18033688011112042f  /* (1/sqrt(64)) * log2(e) */
#define MSHIFT   12.0f

static __device__ inline u16 f2bf(float f) {
    union { float f; unsigned int u; } v; v.f = f;
    unsigned int u = v.u;
    unsigned int r = (u + 0x7FFFu + ((u >> 16) & 1u)) >> 16;  // RNE
    return (u16)r;
}

static __device__ inline u32 cvt_pk_bf16(float lo, float hi) {
    u32 r;
    asm volatile("v_cvt_pk_bf16_f32 %0, %1, %2" : "=v"(r) : "v"(lo), "v"(hi));
    return r;
}

static __device__ __forceinline__ void gl_lds16(const u16* g, u16* l) {
    __builtin_amdgcn_global_load_lds(
        (const __attribute__((address_space(1))) void*)g,
        (__attribute__((address_space(3))) void*)l, 16, 0, 0);
}

// ---------------- K0a: transpose Wq/Wk/Wv [H,E,D] f32 -> WT [3*1024][1024] bf16 ----------------
__global__ __launch_bounds__(256) void transpose_w_kernel(
    const float* __restrict__ Wq, const float* __restrict__ Wk, const float* __restrict__ Wv,
    u16* __restrict__ WT)
{
    const int z = blockIdx.z;
    const int h = blockIdx.y;
    const int e0 = blockIdx.x * 64;
    const float* W = (z == 0) ? Wq : (z == 1) ? Wk : Wv;
    const float sc = (z == 0) ? QSCALE_F : 1.0f;
    __shared__ float t_lds[64][68];
    const int tid = threadIdx.x;
#pragma unroll
    for (int it = 0; it < 4; ++it) {
        int s = tid + it * 256;
        int i = s >> 4, d4 = (s & 15) * 4;
        const float4 v = *reinterpret_cast<const float4*>(&W[((size_t)h * EE + e0 + i) * DD + d4]);
        t_lds[i][d4 + 0] = v.x; t_lds[i][d4 + 1] = v.y;
        t_lds[i][d4 + 2] = v.z; t_lds[i][d4 + 3] = v.w;
    }
    __syncthreads();
#pragma unroll
    for (int it = 0; it < 4; ++it) {
        int s = tid + it * 256;
        int d = s >> 4, i4 = (s & 15) * 4;
        u16x4 o;
        o[0] = f2bf(t_lds[i4 + 0][d] * sc); o[1] = f2bf(t_lds[i4 + 1][d] * sc);
        o[2] = f2bf(t_lds[i4 + 2][d] * sc); o[3] = f2bf(t_lds[i4 + 3][d] * sc);
        *reinterpret_cast<u16x4*>(&WT[((size_t)z * 1024 + h * 64 + d) * EE + e0 + i4]) = o;
    }
}

// ---------------- K0b: W2T[e][h*D+d] = sum_o Wo[h,d,o]*Wf[h*O+o,e]; b2 ----------------
__global__ __launch_bounds__(256) void build_w2t_kernel(
    const float* __restrict__ Wo, const float* __restrict__ bo,
    const float* __restrict__ Wf, const float* __restrict__ bfin,
    u16* __restrict__ W2T, float* __restrict__ b2)
{
    const int h = blockIdx.y;
    const int e0 = blockIdx.x * 64;
    __shared__ float wo_lds[64][65];  // [d][o]
    __shared__ float wf_lds[64][65];  // [o][i]
    const int tid = threadIdx.x;
#pragma unroll
    for (int it = 0; it < 4; ++it) {
        int s = tid + it * 256;
        int r = s >> 4, c4 = (s & 15) * 4;
        const float4 a = *reinterpret_cast<const float4*>(&Wo[((size_t)h * 64 + r) * 64 + c4]);
        wo_lds[r][c4 + 0] = a.x; wo_lds[r][c4 + 1] = a.y; wo_lds[r][c4 + 2] = a.z; wo_lds[r][c4 + 3] = a.w;
        const float4 b = *reinterpret_cast<const float4*>(&Wf[((size_t)(h * 64 + r)) * EE + e0 + c4]);
        wf_lds[r][c4 + 0] = b.x; wf_lds[r][c4 + 1] = b.y; wf_lds[r][c4 + 2] = b.z; wf_lds[r][c4 + 3] = b.w;
    }
    __syncthreads();
    const int d = tid & 63;
    const int i0 = (tid >> 6) * 16;
#pragma unroll
    for (int ii = 0; ii < 16; ++ii) {
        int i = i0 + ii;
        float acc = 0.f;
#pragma unroll 8
        for (int o = 0; o < 64; ++o) acc += wo_lds[d][o] * wf_lds[o][i];
        W2T[((size_t)(e0 + i)) * 1024 + h * 64 + d] = f2bf(acc);
    }
    if (tid < 64) {
        int i = tid;
        float acc = 0.f;
        for (int o = 0; o < 64; ++o) acc += bo[h * 64 + o] * wf_lds[o][i];
        if (h == 0) acc += bfin[e0 + i];
        atomicAdd(&b2[e0 + i], acc);
    }
}

// ---------------- K0c: kbias[b][t] = kmask ? -MSHIFT : -1e38 ----------------
__global__ __launch_bounds__(256) void kbias_kernel(const float* __restrict__ km, float* __restrict__ kb)
{
    int i = blockIdx.x * 256 + threadIdx.x;
    if (i < BB * SS) kb[i] = (km[i] != 0.f) ? -MSHIFT : -1e38f;
}

// ---------------- K1: QKV GEMM — 128x64 tile, 48 KB LDS (3 blocks/CU), counted-vmcnt ----------------
// VMEM issue order per iter: STAGEB(t+1) BEFORE LOADA(t+2) so vmcnt(4) drains {A(t+1)x4, B(t+1)x1}.
__global__ __launch_bounds__(512, 6) void gemm_qkv_kernel(
    const float* __restrict__ query, const float* __restrict__ key, const float* __restrict__ value,
    const u16* __restrict__ WT,
    const float* __restrict__ bq, const float* __restrict__ bk, const float* __restrict__ bv,
    u16* __restrict__ qbf, u16* __restrict__ kbf, u16* __restrict__ vbf)
{
    const int id = blockIdx.x;
    const int xcd = id & 7, idx = id >> 3;       // idx 0..191
    const int p = xcd * 12 + (idx >> 4);         // panel 0..95 (z,m)
    const int z = p >> 5;
    const int m0 = (p & 31) * 128;
    const int n0 = (idx & 15) * 64;

    const float* A   = (z == 0) ? query : (z == 1) ? key : value;
    const float* bia = (z == 0) ? bq    : (z == 1) ? bk  : bv;
    u16* outp        = (z == 0) ? qbf   : (z == 1) ? kbf : vbf;
    const float bsc  = (z == 0) ? QSCALE_F : 1.0f;
    const u16* BT = WT + (size_t)z * 1024 * 1024;

    __shared__ u16 a_lds[2][128][64];   // 32 KB
    __shared__ u16 b_lds[2][64][64];    // 16 KB

    const int tid = threadIdx.x;
    const int lane = tid & 63;
    const int w = tid >> 6;              // 8 waves
    const int wm = w >> 1, wn = w & 1;   // wave tile: 32 rows x 32 cols
    const int lrow = lane & 15;
    const int lgrp = lane >> 4;

    f32x4 acc[2][2] = {};
    float4 ar0[4], ar1[4];

#define LOADA(ar, k0s)                                                                     \
    do {                                                                                   \
        _Pragma("unroll")                                                                  \
        for (int it = 0; it < 4; ++it) {                                                   \
            int s_ = tid + it * 512;                                                       \
            int row_ = s_ >> 4, c4_ = (s_ & 15) * 4;                                       \
            ar[it] = *reinterpret_cast<const float4*>(&A[(size_t)(m0 + row_) * 1024 + (k0s) + c4_]); \
        }                                                                                  \
    } while (0)

#define STAGEB(bufi, k0s)                                                                  \
    do {                                                                                   \
        int s_ = tid;                                                                      \
        int row_ = s_ >> 3;                                                                \
        int sc_ = ((((s_ & 7) * 16) ^ ((row_ & 7) << 4)) >> 1);                            \
        gl_lds16(&BT[(size_t)(n0 + row_) * 1024 + (k0s) + sc_], &b_lds[bufi][0][0] + s_ * 8); \
    } while (0)

#define WRITEA(bufi, ar)                                                                   \
    do {                                                                                   \
        _Pragma("unroll")                                                                  \
        for (int it = 0; it < 4; ++it) {                                                   \
            int s_ = tid + it * 512;                                                       \
            int row_ = s_ >> 4, c8_ = (s_ & 15) * 8;                                       \
            u32x2 o_;                                                                      \
            o_[0] = cvt_pk_bf16(ar[it].x, ar[it].y);                                       \
            o_[1] = cvt_pk_bf16(ar[it].z, ar[it].w);                                       \
            *reinterpret_cast<u32x2*>(reinterpret_cast<char*>(&a_lds[bufi][0][0]) + row_ * 128 + (c8_ ^ ((row_ & 7) << 4))) = o_; \
        }                                                                                  \
    } while (0)

#define COMPUTE(abuf, bbuf)                                                                \
    do {                                                                                   \
        const char* ab_ = reinterpret_cast<const char*>(&a_lds[abuf][0][0]);               \
        const char* bb_ = reinterpret_cast<const char*>(&b_lds[bbuf][0][0]);               \
        _Pragma("unroll")                                                                  \
        for (int kk = 0; kk < 2; ++kk) {                                                   \
            bf16x8 af[2], bfr[2];                                                          \
            _Pragma("unroll")                                                              \
            for (int i = 0; i < 2; ++i) {                                                  \
                int row = wm * 32 + i * 16 + lrow;                                         \
                af[i] = *reinterpret_cast<const bf16x8*>(ab_ + row * 128 + ((kk * 64 + lgrp * 16) ^ ((row & 7) << 4))); \
            }                                                                              \
            _Pragma("unroll")                                                              \
            for (int j = 0; j < 2; ++j) {                                                  \
                int row = wn * 32 + j * 16 + lrow;                                         \
                bfr[j] = *reinterpret_cast<const bf16x8*>(bb_ + row * 128 + ((kk * 64 + lgrp * 16) ^ ((row & 7) << 4))); \
            }                                                                              \
            _Pragma("unroll")                                                              \
            for (int i = 0; i < 2; ++i)                                                    \
                _Pragma("unroll")                                                          \
                for (int j = 0; j < 2; ++j)                                                \
                    acc[i][j] = __builtin_amdgcn_mfma_f32_16x16x32_bf16(af[i], bfr[j], acc[i][j], 0, 0, 0); \
        }                                                                                  \
    } while (0)

    // prologue: order A0(4), B0(1), A1(4); vmcnt(4) drains A0+B0
    LOADA(ar0, 0);
    STAGEB(0, 0);
    LOADA(ar1, 64);
    asm volatile("s_waitcnt vmcnt(4)" ::: "memory");
    WRITEA(0, ar0);
    asm volatile("s_waitcnt lgkmcnt(0)" ::: "memory");
    __builtin_amdgcn_s_barrier();

#pragma unroll
    for (int t = 0; t < 16; ++t) {
        if (t < 15) STAGEB((t + 1) & 1, (t + 1) * 64);   // B before A: queue order for counted drain
        if (t < 14) {
            if ((t & 1) == 0) LOADA(ar0, (t + 2) * 64);
            else              LOADA(ar1, (t + 2) * 64);
        }

        COMPUTE(t & 1, t & 1);

        if (t < 14)       asm volatile("s_waitcnt vmcnt(4)" ::: "memory");
        else if (t == 14) asm volatile("s_waitcnt vmcnt(0)" ::: "memory");
        if (t < 15) {
            if ((t & 1) == 0) WRITEA(1, ar1);
            else              WRITEA(0, ar0);
            asm volatile("s_waitcnt lgkmcnt(0)" ::: "memory");
            __builtin_amdgcn_s_barrier();
        }
    }
#undef LOADA
#undef STAGEB
#undef WRITEA
#undef COMPUTE

#pragma unroll
    for (int i = 0; i < 2; ++i) {
#pragma unroll
        for (int j = 0; j < 2; ++j) {
            int n = n0 + wn * 32 + j * 16 + lrow;
            int h = n >> 6, d = n & 63;
            float bb = bia[n] * bsc;
#pragma unroll
            for (int r = 0; r < 4; ++r) {
                int m = m0 + wm * 32 + i * 16 + lgrp * 4 + r;
                int b = m >> 11, srow = m & 2047;
                outp[((size_t)(b * HH + h) * SS + srow) * DD + d] = f2bf(acc[i][j][r] + bb);
            }
        }
    }
}

// ---------------- K1b: transpose V [B,H,S,D] -> [B,H,D,S] (bf16) ----------------
__global__ __launch_bounds__(256) void transpose_v_kernel(
    const u16* __restrict__ vbf, u16* __restrict__ vtg)
{
    const int s0 = blockIdx.x * 64;
    const int bh = blockIdx.y;
    __shared__ u16 t_lds[64][72];
    const int tid = threadIdx.x;
#pragma unroll
    for (int rr = 0; rr < 2; ++rr) {
        int idx = tid + rr * 256;
        int row = idx >> 3, c8 = (idx & 7) * 8;
        *reinterpret_cast<u16x8*>(&t_lds[row][c8]) =
            *reinterpret_cast<const u16x8*>(&vbf[((size_t)bh * SS + s0 + row) * DD + c8]);
    }
    __syncthreads();
#pragma unroll
    for (int rr = 0; rr < 2; ++rr) {
        int idx = tid + rr * 256;
        int d = idx >> 3, tt = (idx & 7) * 8;
        u16x8 o;
#pragma unroll
        for (int j = 0; j < 8; ++j) o[j] = t_lds[tt + j][d];
        *reinterpret_cast<u16x8*>(&vtg[((size_t)bh * DD + d) * SS + s0 + tt]) = o;
    }
}

// ---------------- K2: flash attention — R17 (kbias in LDS, vmcnt-clean loop) ----------------
__global__ __launch_bounds__(512, 4) void attn_kernel(
    const u16* __restrict__ qbf, const u16* __restrict__ kbf, const u16* __restrict__ vtg,
    const float* __restrict__ kbias, const float* __restrict__ qmask,
    u16* __restrict__ att)
{
    const int id = blockIdx.x;
    const int wg = (id & 7) * 64 + (id >> 3);   // XCD-chunked: 4 bh per XCD
    const int bh = wg >> 4, qt = wg & 15;
    const int b = bh >> 4, h = bh & 15;

    const int tid = threadIdx.x;
    const int w = tid >> 6;
    const int lane = tid & 63;
    const int ql = lane & 31, hi = lane >> 5;
    const int qw = w & 3, th = w >> 2;
    const int q0 = qt * 128 + qw * 32;

    __shared__ u16 sm[8][4096];
    __shared__ float kb_lds[2048];

    const size_t bhoff = (size_t)bh * SS * DD;
    const u16* Kb = kbf + bhoff;                    // [2048][64]
    const u16* Vb = vtg + (size_t)bh * DD * SS;     // [64][2048]

    *reinterpret_cast<float4*>(&kb_lds[tid * 4]) =
        *reinterpret_cast<const float4*>(&kbias[(size_t)b * SS + tid * 4]);

    bf16x8 aq[4];
#pragma unroll
    for (int c = 0; c < 4; ++c)
        aq[c] = *reinterpret_cast<const bf16x8*>(&qbf[bhoff + (size_t)(q0 + ql) * DD + c * 16 + hi * 8]);

    f32x16 acc0 = {}, acc1 = {};
    const f32x16 fz = {};
    float l_run = 0.f;

    const int r_ = tid >> 3;
    const int lch_ = (((tid & 7) * 16) ^ ((r_ & 7) << 4)) >> 1;

#define STAGE(bufi, t64)                                                                   \
    do {                                                                                   \
        gl_lds16(Kb + (size_t)((t64) + r_) * 64 + lch_,          &sm[0 + (bufi)][tid * 8]); \
        gl_lds16(Vb + (size_t)r_ * SS + (t64) + lch_,            &sm[2 + (bufi)][tid * 8]); \
        gl_lds16(Kb + (size_t)(1024 + (t64) + r_) * 64 + lch_,   &sm[4 + (bufi)][tid * 8]); \
        gl_lds16(Vb + (size_t)r_ * SS + 1024 + (t64) + lch_,     &sm[6 + (bufi)][tid * 8]); \
    } while (0)

    STAGE(0, 0);
    asm volatile("s_waitcnt vmcnt(0)" ::: "memory");
    __syncthreads();

    const float* kbl = kb_lds + th * 1024;
    int cur = 0;
    for (int ti = 0; ti < 16; ++ti) {
        const int t0 = ti * 64;
        if (ti < 15) STAGE(cur ^ 1, t0 + 64);

        const char* kbase = reinterpret_cast<const char*>(&sm[th * 4 + cur][0]);
        const char* vbase = reinterpret_cast<const char*>(&sm[th * 4 + 2 + cur][0]);

        float4 km0[4], km1[4];
#pragma unroll
        for (int g = 0; g < 4; ++g) {
            km0[g] = *reinterpret_cast<const float4*>(kbl + t0 + g * 8 + hi * 4);
            km1[g] = *reinterpret_cast<const float4*>(kbl + t0 + 32 + g * 8 + hi * 4);
        }

        const int row0 = ql, row1 = 32 + ql;
        const int swz0 = (row0 & 7) << 4, swz1 = (row1 & 7) << 4;
        f32x16 s0, s1;
        {
            bf16x8 kf0 = *reinterpret_cast<const bf16x8*>(kbase + row0 * 128 + ((0 * 32 + hi * 16) ^ swz0));
            bf16x8 kf1 = *reinterpret_cast<const bf16x8*>(kbase + row1 * 128 + ((0 * 32 + hi * 16) ^ swz1));
            s0 = __builtin_amdgcn_mfma_f32_32x32x16_bf16(kf0, aq[0], fz, 0, 0, 0);
            s1 = __builtin_amdgcn_mfma_f32_32x32x16_bf16(kf1, aq[0], fz, 0, 0, 0);
        }
#pragma unroll
        for (int c = 1; c < 4; ++c) {
            bf16x8 kf0 = *reinterpret_cast<const bf16x8*>(kbase + row0 * 128 + ((c * 32 + hi * 16) ^ swz0));
            bf16x8 kf1 = *reinterpret_cast<const bf16x8*>(kbase + row1 * 128 + ((c * 32 + hi * 16) ^ swz1));
            s0 = __builtin_amdgcn_mfma_f32_32x32x16_bf16(kf0, aq[c], s0, 0, 0, 0);
            s1 = __builtin_amdgcn_mfma_f32_32x32x16_bf16(kf1, aq[c], s1, 0, 0, 0);
        }

        float p0[16], p1[16];
        float ps0 = 0.f, ps1 = 0.f, ps2 = 0.f, ps3 = 0.f;
#pragma unroll
        for (int r = 0; r < 16; ++r) {
            float kv0 = (r & 1) ? ((r & 2) ? km0[r >> 2].w : km0[r >> 2].y)
                                : ((r & 2) ? km0[r >> 2].z : km0[r >> 2].x);
            float kv1 = (r & 1) ? ((r & 2) ? km1[r >> 2].w : km1[r >> 2].y)
                                : ((r & 2) ? km1[r >> 2].z : km1[r >> 2].x);
            float e0 = __builtin_amdgcn_exp2f(s0[r] + kv0);
            float e1 = __builtin_amdgcn_exp2f(s1[r] + kv1);
            p0[r] = e0; p1[r] = e1;
            if (r & 1) { ps1 += e0; ps3 += e1; } else { ps0 += e0; ps2 += e1; }
        }
        l_run += (ps0 + ps1) + (ps2 + ps3);

        bf16x8 pw[4];
#pragma unroll
        for (int hf = 0; hf < 2; ++hf) {
            {
                u32 x1 = cvt_pk_bf16(p0[hf * 8 + 0], p0[hf * 8 + 1]);
                u32 x2 = cvt_pk_bf16(p0[hf * 8 + 2], p0[hf * 8 + 3]);
                u32 y1 = cvt_pk_bf16(p0[hf * 8 + 4], p0[hf * 8 + 5]);
                u32 y2 = cvt_pk_bf16(p0[hf * 8 + 6], p0[hf * 8 + 7]);
                u32x2 sA = __builtin_amdgcn_permlane32_swap(x1, y1, false, false);
                u32x2 sB = __builtin_amdgcn_permlane32_swap(x2, y2, false, false);
                u32x4 fr; fr[0] = sA[0]; fr[1] = sB[0]; fr[2] = sA[1]; fr[3] = sB[1];
                pw[hf] = __builtin_bit_cast(bf16x8, fr);
            }
            {
                u32 x1 = cvt_pk_bf16(p1[hf * 8 + 0], p1[hf * 8 + 1]);
                u32 x2 = cvt_pk_bf16(p1[hf * 8 + 2], p1[hf * 8 + 3]);
                u32 y1 = cvt_pk_bf16(p1[hf * 8 + 4], p1[hf * 8 + 5]);
                u32 y2 = cvt_pk_bf16(p1[hf * 8 + 6], p1[hf * 8 + 7]);
                u32x2 sA = __builtin_amdgcn_permlane32_swap(x1, y1, false, false);
                u32x2 sB = __builtin_amdgcn_permlane32_swap(x2, y2, false, false);
                u32x4 fr; fr[0] = sA[0]; fr[1] = sB[0]; fr[2] = sA[1]; fr[3] = sB[1];
                pw[2 + hf] = __builtin_bit_cast(bf16x8, fr);
            }
        }

#pragma unroll
        for (int cc = 0; cc < 4; ++cc) {
            bf16x8 vf0 = *reinterpret_cast<const bf16x8*>(vbase + row0 * 128 + ((cc * 32 + hi * 16) ^ swz0));
            bf16x8 vf1 = *reinterpret_cast<const bf16x8*>(vbase + row1 * 128 + ((cc * 32 + hi * 16) ^ swz1));
            acc0 = __builtin_amdgcn_mfma_f32_32x32x16_bf16(vf0, pw[cc], acc0, 0, 0, 0);
            acc1 = __builtin_amdgcn_mfma_f32_32x32x16_bf16(vf1, pw[cc], acc1, 0, 0, 0);
        }

        asm volatile("s_waitcnt vmcnt(0)" ::: "memory");
        __syncthreads();
        cur ^= 1;
    }
#undef STAGE

    float* cb = reinterpret_cast<float*>(&sm[0][0]);
    const int ci = (qw * 64 + lane) * 34;
    if (th == 1) {
#pragma unroll
        for (int r = 0; r < 16; ++r) { cb[ci + r] = acc0[r]; cb[ci + 16 + r] = acc1[r]; }
        cb[ci + 32] = l_run;
    }
    __syncthreads();
    if (th == 0) {
#pragma unroll
        for (int r = 0; r < 16; ++r) { acc0[r] += cb[ci + r]; acc1[r] += cb[ci + 16 + r]; }
        l_run += cb[ci + 32];

        float l1 = l_run + __shfl_xor(l_run, 32);
        float qm = qmask[(size_t)b * SS + q0 + ql];
        float inv = (l1 > 0.f && qm != 0.f) ? 1.f / l1 : 0.f;
        u16* orow = att + ((size_t)b * SS + q0 + ql) * 1024 + h * 64;
#pragma unroll
        for (int c = 0; c < 4; ++c)
#pragma unroll
            for (int pp = 0; pp < 2; ++pp) {
                int d0 = 8 * c + 4 * hi + 2 * pp;
                u32 w0 = cvt_pk_bf16(acc0[4 * c + 2 * pp] * inv, acc0[4 * c + 2 * pp + 1] * inv);
                u32 w1 = cvt_pk_bf16(acc1[4 * c + 2 * pp] * inv, acc1[4 * c + 2 * pp + 1] * inv);
                *reinterpret_cast<u32*>(orow + d0) = w0;
                *reinterpret_cast<u32*>(orow + 32 + d0) = w1;
            }
    }
}

// ---------------- K3: final GEMM — 512 threads (8 waves), counted-vmcnt depth-2 pipeline ----------------
__global__ __launch_bounds__(512, 2) void gemm_final_kernel(
    const u16* __restrict__ A, const u16* __restrict__ BT,
    const float* __restrict__ b2, float* __restrict__ out)
{
    const int id = blockIdx.x;
    const int xcd = id & 7, idx = id >> 3;       // idx 0..31
    const int p = xcd * 4 + (idx >> 3);          // m-panel 0..31
    const int m0 = p * 128;
    const int n0 = (idx & 7) * 128;

    __shared__ u16 a_lds[3][128][64];
    __shared__ u16 b_lds[3][128][64];

    const int tid = threadIdx.x;
    const int lane = tid & 63;
    const int w = tid >> 6;              // 8 waves
    const int wm = w >> 1, wn = w & 1;   // wave tile: 32 rows x 64 cols
    const int lrow = lane & 15;
    const int lgrp = lane >> 4;

    f32x4 acc[2][4] = {};

#define STAGEF(bufi, k0s)                                                                  \
    do {                                                                                   \
        _Pragma("unroll")                                                                  \
        for (int it = 0; it < 2; ++it) {                                                   \
            int s_ = tid + it * 512;                                                       \
            int row_ = s_ >> 3;                                                            \
            int sc_ = ((((s_ & 7) * 16) ^ ((row_ & 7) << 4)) >> 1);                        \
            gl_lds16(&A[(size_t)(m0 + row_) * 1024 + (k0s) + sc_], &a_lds[bufi][0][0] + s_ * 8);  \
            gl_lds16(&BT[(size_t)(n0 + row_) * 1024 + (k0s) + sc_], &b_lds[bufi][0][0] + s_ * 8); \
        }                                                                                  \
    } while (0)

#define COMPUTEF(bufi)                                                                     \
    do {                                                                                   \
        const char* ab_ = reinterpret_cast<const char*>(&a_lds[bufi][0][0]);               \
        const char* bb_ = reinterpret_cast<const char*>(&b_lds[bufi][0][0]);               \
        _Pragma("unroll")                                                                  \
        for (int kk = 0; kk < 2; ++kk) {                                                   \
            bf16x8 af[2], bfr[4];                                                          \
            _Pragma("unroll")                                                              \
            for (int i = 0; i < 2; ++i) {                                                  \
                int row = wm * 32 + i * 16 + lrow;                                         \
                af[i] = *reinterpret_cast<const bf16x8*>(ab_ + row * 128 + ((kk * 64 + lgrp * 16) ^ ((row & 7) << 4))); \
            }                                                                              \
            _Pragma("unroll")                                                              \
            for (int j = 0; j < 4; ++j) {                                                  \
                int row = wn * 64 + j * 16 + lrow;                                         \
                bfr[j] = *reinterpret_cast<const bf16x8*>(bb_ + row * 128 + ((kk * 64 + lgrp * 16) ^ ((row & 7) << 4))); \
            }                                                                              \
            _Pragma("unroll")                                                              \
            for (int i = 0; i < 2; ++i)                                                    \
                _Pragma("unroll")                                                          \
                for (int j = 0; j < 4; ++j)                                                \
                    acc[i][j] = __builtin_amdgcn_mfma_f32_16x16x32_bf16(af[i], bfr[j], acc[i][j], 0, 0, 0); \
        }                                                                                  \
    } while (0)

    STAGEF(0, 0);
    STAGEF(1, 64);
    asm volatile("s_waitcnt vmcnt(4)" ::: "memory");
    __builtin_amdgcn_s_barrier();

#pragma unroll
    for (int t = 0; t < 16; ++t) {
        if (t < 14) STAGEF((t + 2) % 3, (t + 2) * 64);

        COMPUTEF(t % 3);

        if (t < 14)       asm volatile("s_waitcnt vmcnt(4)" ::: "memory");
        else if (t == 14) asm volatile("s_waitcnt vmcnt(0)" ::: "memory");
        if (t < 15) __builtin_amdgcn_s_barrier();
    }
#undef STAGEF
#undef COMPUTEF

#pragma unroll
    for (int i = 0; i < 2; ++i) {
#pragma unroll
        for (int j = 0; j < 4; ++j) {
            int n = n0 + wn * 64 + j * 16 + lrow;
            float bb = b2[n];
#pragma unroll
            for (int r = 0; r < 4; ++r) {
                int m = m0 + wm * 32 + i * 16 + lgrp * 4 + r;
                out[(size_t)m * 1024 + n] = acc[i][j][r] + bb;
            }
        }
    }
}

extern "C" void kernel_launch(void* const* d_in, const int* in_sizes, int n_in,
                              void* d_out, int out_size, void* d_ws, size_t ws_size,
                              hipStream_t stream) {
    const float* query = (const float*)d_in[0];
    const float* key   = (const float*)d_in[1];
    const float* value = (const float*)d_in[2];
    const float* qmask = (const float*)d_in[3];
    const float* kmask = (const float*)d_in[4];
    const float* Wq = (const float*)d_in[5];
    const float* bq = (const float*)d_in[6];
    const float* Wk = (const float*)d_in[7];
    const float* bk = (const float*)d_in[8];
    const float* Wv = (const float*)d_in[9];
    const float* bv = (const float*)d_in[10];
    const float* Wo = (const float*)d_in[11];
    const float* bo = (const float*)d_in[12];
    const float* Wf = (const float*)d_in[13];
    const float* bfin = (const float*)d_in[14];
    float* out = (float*)d_out;

    char* ws = (char*)d_ws;
    u16*   WT  = (u16*)  (ws + 0);          // 6291456
    u16*   W2T = (u16*)  (ws + 6291456);    // 2097152
    float* b2  = (float*)(ws + 8388608);    // 4096
    u16*   qbf = (u16*)  (ws + 8392704);    // 8388608
    u16*   kbf = (u16*)  (ws + 16781312);   // 8388608
    u16*   vbf = (u16*)  (ws + 25169920);   // 8388608
    u16*   att = (u16*)  (ws + 33558528);   // 8388608
    u16*   vtg = (u16*)  (ws + 41947136);   // 8388608
    float* kb  = (float*)(ws + 50335744);   // 16384  (end ~50.4 MB)

    hipMemsetAsync(b2, 0, 1024 * sizeof(float), stream);
    transpose_w_kernel<<<dim3(16, 16, 3), 256, 0, stream>>>(Wq, Wk, Wv, WT);
    build_w2t_kernel<<<dim3(16, 16), 256, 0, stream>>>(Wo, bo, Wf, bfin, W2T, b2);
    kbias_kernel<<<dim3(16), 256, 0, stream>>>(kmask, kb);
    gemm_qkv_kernel<<<dim3(1536), 512, 0, stream>>>(query, key, value, WT, bq, bk, bv, qbf, kbf, vbf);
    transpose_v_kernel<<<dim3(32, 32), 256, 0, stream>>>(vbf, vtg);
    attn_kernel<<<dim3(512), 512, 0, stream>>>(qbf, kbf, vtg, kb, qmask, att);
    gemm_final_kernel<<<dim3(256), 512, 0, stream>>>(att, W2T, b2, out);
}

// Round 19
// 131.197 us; speedup vs baseline: 1.0669x; 1.0669x over previous
//
#include <hip/hip_runtime.h>

typedef unsigned short u16;
typedef unsigned int u32;
typedef __bf16 bf16x8 __attribute__((ext_vector_type(8)));
typedef float f32x4 __attribute__((ext_vector_type(4)));
typedef float f32x16 __attribute__((ext_vector_type(16)));
typedef unsigned short u16x4 __attribute__((ext_vector_type(4)));
typedef unsigned short u16x8 __attribute__((ext_vector_type(8)));
typedef unsigned int u32x2 __attribute__((ext_vector_type(2)));
typedef unsigned int u32x4 __attribute__((ext_vector_type(4)));

#define BB 2
#define SS 2048
#define EE 1024
#define HH 16
#define DD 64

#define QSCALE_F 0.18033688011112042f  /* (1/sqrt(64)) * log2(e) */
#define MSHIFT   12.0f

static __device__ inline u16 f2bf(float f) {
    union { float f; unsigned int u; } v; v.f = f;
    unsigned int u = v.u;
    unsigned int r = (u + 0x7FFFu + ((u >> 16) & 1u)) >> 16;  // RNE
    return (u16)r;
}

static __device__ inline u32 cvt_pk_bf16(float lo, float hi) {
    u32 r;
    asm volatile("v_cvt_pk_bf16_f32 %0, %1, %2" : "=v"(r) : "v"(lo), "v"(hi));
    return r;
}

static __device__ __forceinline__ void gl_lds16(const u16* g, u16* l) {
    __builtin_amdgcn_global_load_lds(
        (const __attribute__((address_space(1))) void*)g,
        (__attribute__((address_space(3))) void*)l, 16, 0, 0);
}

// ---------------- K0a: transpose Wq/Wk/Wv [H,E,D] f32 -> WT [3*1024][1024] bf16 ----------------
__global__ __launch_bounds__(256) void transpose_w_kernel(
    const float* __restrict__ Wq, const float* __restrict__ Wk, const float* __restrict__ Wv,
    u16* __restrict__ WT)
{
    const int z = blockIdx.z;
    const int h = blockIdx.y;
    const int e0 = blockIdx.x * 64;
    const float* W = (z == 0) ? Wq : (z == 1) ? Wk : Wv;
    const float sc = (z == 0) ? QSCALE_F : 1.0f;
    __shared__ float t_lds[64][68];
    const int tid = threadIdx.x;
#pragma unroll
    for (int it = 0; it < 4; ++it) {
        int s = tid + it * 256;
        int i = s >> 4, d4 = (s & 15) * 4;
        const float4 v = *reinterpret_cast<const float4*>(&W[((size_t)h * EE + e0 + i) * DD + d4]);
        t_lds[i][d4 + 0] = v.x; t_lds[i][d4 + 1] = v.y;
        t_lds[i][d4 + 2] = v.z; t_lds[i][d4 + 3] = v.w;
    }
    __syncthreads();
#pragma unroll
    for (int it = 0; it < 4; ++it) {
        int s = tid + it * 256;
        int d = s >> 4, i4 = (s & 15) * 4;
        u16x4 o;
        o[0] = f2bf(t_lds[i4 + 0][d] * sc); o[1] = f2bf(t_lds[i4 + 1][d] * sc);
        o[2] = f2bf(t_lds[i4 + 2][d] * sc); o[3] = f2bf(t_lds[i4 + 3][d] * sc);
        *reinterpret_cast<u16x4*>(&WT[((size_t)z * 1024 + h * 64 + d) * EE + e0 + i4]) = o;
    }
}

// ---------------- K0b: W2T[e][h*D+d] = sum_o Wo[h,d,o]*Wf[h*O+o,e]; b2 ----------------
__global__ __launch_bounds__(256) void build_w2t_kernel(
    const float* __restrict__ Wo, const float* __restrict__ bo,
    const float* __restrict__ Wf, const float* __restrict__ bfin,
    u16* __restrict__ W2T, float* __restrict__ b2)
{
    const int h = blockIdx.y;
    const int e0 = blockIdx.x * 64;
    __shared__ float wo_lds[64][65];  // [d][o]
    __shared__ float wf_lds[64][65];  // [o][i]
    const int tid = threadIdx.x;
#pragma unroll
    for (int it = 0; it < 4; ++it) {
        int s = tid + it * 256;
        int r = s >> 4, c4 = (s & 15) * 4;
        const float4 a = *reinterpret_cast<const float4*>(&Wo[((size_t)h * 64 + r) * 64 + c4]);
        wo_lds[r][c4 + 0] = a.x; wo_lds[r][c4 + 1] = a.y; wo_lds[r][c4 + 2] = a.z; wo_lds[r][c4 + 3] = a.w;
        const float4 b = *reinterpret_cast<const float4*>(&Wf[((size_t)(h * 64 + r)) * EE + e0 + c4]);
        wf_lds[r][c4 + 0] = b.x; wf_lds[r][c4 + 1] = b.y; wf_lds[r][c4 + 2] = b.z; wf_lds[r][c4 + 3] = b.w;
    }
    __syncthreads();
    const int d = tid & 63;
    const int i0 = (tid >> 6) * 16;
#pragma unroll
    for (int ii = 0; ii < 16; ++ii) {
        int i = i0 + ii;
        float acc = 0.f;
#pragma unroll 8
        for (int o = 0; o < 64; ++o) acc += wo_lds[d][o] * wf_lds[o][i];
        W2T[((size_t)(e0 + i)) * 1024 + h * 64 + d] = f2bf(acc);
    }
    if (tid < 64) {
        int i = tid;
        float acc = 0.f;
        for (int o = 0; o < 64; ++o) acc += bo[h * 64 + o] * wf_lds[o][i];
        if (h == 0) acc += bfin[e0 + i];
        atomicAdd(&b2[e0 + i], acc);
    }
}

// ---------------- K0c: kbias[b][t] = kmask ? -MSHIFT : -1e38 ----------------
__global__ __launch_bounds__(256) void kbias_kernel(const float* __restrict__ km, float* __restrict__ kb)
{
    int i = blockIdx.x * 256 + threadIdx.x;
    if (i < BB * SS) kb[i] = (km[i] != 0.f) ? -MSHIFT : -1e38f;
}

// ---------------- K1: QKV GEMM — 512 threads (8 waves), counted-vmcnt depth-2 pipeline ----------------
__global__ __launch_bounds__(512, 4) void gemm_qkv_kernel(
    const float* __restrict__ query, const float* __restrict__ key, const float* __restrict__ value,
    const u16* __restrict__ WT,
    const float* __restrict__ bq, const float* __restrict__ bk, const float* __restrict__ bv,
    u16* __restrict__ qbf, u16* __restrict__ kbf, u16* __restrict__ vbf)
{
    const int id = blockIdx.x;
    const int xcd = id & 7, idx = id >> 3;       // idx 0..95
    const int p = xcd * 12 + (idx >> 3);         // panel 0..95
    const int z = p >> 5;
    const int m0 = (p & 31) * 128;
    const int n0 = (idx & 7) * 128;

    const float* A   = (z == 0) ? query : (z == 1) ? key : value;
    const float* bia = (z == 0) ? bq    : (z == 1) ? bk  : bv;
    u16* outp        = (z == 0) ? qbf   : (z == 1) ? kbf : vbf;
    const float bsc  = (z == 0) ? QSCALE_F : 1.0f;
    const u16* BT = WT + (size_t)z * 1024 * 1024;

    __shared__ u16 a_lds[2][128][64];   // 32 KB, swizzled content
    __shared__ u16 b_lds[3][128][64];   // 48 KB

    const int tid = threadIdx.x;
    const int lane = tid & 63;
    const int w = tid >> 6;              // 8 waves
    const int wm = w >> 1, wn = w & 1;   // wave tile: 32 rows x 64 cols
    const int lrow = lane & 15;
    const int lgrp = lane >> 4;

    f32x4 acc[2][4] = {};
    float4 ar0[4], ar1[4];

#define LOADA(ar, k0s)                                                                     \
    do {                                                                                   \
        _Pragma("unroll")                                                                  \
        for (int it = 0; it < 4; ++it) {                                                   \
            int s_ = tid + it * 512;                                                       \
            int row_ = s_ >> 4, c4_ = (s_ & 15) * 4;                                       \
            ar[it] = *reinterpret_cast<const float4*>(&A[(size_t)(m0 + row_) * 1024 + (k0s) + c4_]); \
        }                                                                                  \
    } while (0)

#define STAGEB(bufi, k0s)                                                                  \
    do {                                                                                   \
        _Pragma("unroll")                                                                  \
        for (int it = 0; it < 2; ++it) {                                                   \
            int s_ = tid + it * 512;                                                       \
            int row_ = s_ >> 3;                                                            \
            int sc_ = ((((s_ & 7) * 16) ^ ((row_ & 7) << 4)) >> 1);                        \
            gl_lds16(&BT[(size_t)(n0 + row_) * 1024 + (k0s) + sc_], &b_lds[bufi][0][0] + s_ * 8); \
        }                                                                                  \
    } while (0)

#define WRITEA(bufi, ar)                                                                   \
    do {                                                                                   \
        _Pragma("unroll")                                                                  \
        for (int it = 0; it < 4; ++it) {                                                   \
            int s_ = tid + it * 512;                                                       \
            int row_ = s_ >> 4, c8_ = (s_ & 15) * 8;                                       \
            u32x2 o_;                                                                      \
            o_[0] = cvt_pk_bf16(ar[it].x, ar[it].y);                                       \
            o_[1] = cvt_pk_bf16(ar[it].z, ar[it].w);                                       \
            *reinterpret_cast<u32x2*>(reinterpret_cast<char*>(&a_lds[bufi][0][0]) + row_ * 128 + (c8_ ^ ((row_ & 7) << 4))) = o_; \
        }                                                                                  \
    } while (0)

#define COMPUTE(abuf, bbuf)                                                                \
    do {                                                                                   \
        const char* ab_ = reinterpret_cast<const char*>(&a_lds[abuf][0][0]);               \
        const char* bb_ = reinterpret_cast<const char*>(&b_lds[bbuf][0][0]);               \
        _Pragma("unroll")                                                                  \
        for (int kk = 0; kk < 2; ++kk) {                                                   \
            bf16x8 af[2], bfr[4];                                                          \
            _Pragma("unroll")                                                              \
            for (int i = 0; i < 2; ++i) {                                                  \
                int row = wm * 32 + i * 16 + lrow;                                         \
                af[i] = *reinterpret_cast<const bf16x8*>(ab_ + row * 128 + ((kk * 64 + lgrp * 16) ^ ((row & 7) << 4))); \
            }                                                                              \
            _Pragma("unroll")                                                              \
            for (int j = 0; j < 4; ++j) {                                                  \
                int row = wn * 64 + j * 16 + lrow;                                         \
                bfr[j] = *reinterpret_cast<const bf16x8*>(bb_ + row * 128 + ((kk * 64 + lgrp * 16) ^ ((row & 7) << 4))); \
            }                                                                              \
            _Pragma("unroll")                                                              \
            for (int i = 0; i < 2; ++i)                                                    \
                _Pragma("unroll")                                                          \
                for (int j = 0; j < 4; ++j)                                                \
                    acc[i][j] = __builtin_amdgcn_mfma_f32_16x16x32_bf16(af[i], bfr[j], acc[i][j], 0, 0, 0); \
        }                                                                                  \
    } while (0)

    // prologue: tiles 0 and 1 in flight (12 VMEM/thread); wait first 6 -> tile 0 ready
    LOADA(ar0, 0);
    STAGEB(0, 0);
    LOADA(ar1, 64);
    STAGEB(1, 64);
    asm volatile("s_waitcnt vmcnt(6)" ::: "memory");
    WRITEA(0, ar0);
    asm volatile("s_waitcnt lgkmcnt(0)" ::: "memory");
    __builtin_amdgcn_s_barrier();

#pragma unroll
    for (int t = 0; t < 16; ++t) {
        if (t < 14) {
            if ((t & 1) == 0) LOADA(ar0, (t + 2) * 64);
            else              LOADA(ar1, (t + 2) * 64);
            STAGEB((t + 2) % 3, (t + 2) * 64);
        }

        COMPUTE(t & 1, t % 3);

        if (t < 14)      asm volatile("s_waitcnt vmcnt(6)" ::: "memory");
        else if (t == 14) asm volatile("s_waitcnt vmcnt(0)" ::: "memory");
        if (t < 15) {
            if ((t & 1) == 0) WRITEA(1, ar1);
            else              WRITEA(0, ar0);
            asm volatile("s_waitcnt lgkmcnt(0)" ::: "memory");
            __builtin_amdgcn_s_barrier();
        }
    }
#undef LOADA
#undef STAGEB
#undef WRITEA
#undef COMPUTE

#pragma unroll
    for (int i = 0; i < 2; ++i) {
#pragma unroll
        for (int j = 0; j < 4; ++j) {
            int n = n0 + wn * 64 + j * 16 + lrow;
            int h = n >> 6, d = n & 63;
            float bb = bia[n] * bsc;
#pragma unroll
            for (int r = 0; r < 4; ++r) {
                int m = m0 + wm * 32 + i * 16 + lgrp * 4 + r;
                int b = m >> 11, srow = m & 2047;
                outp[((size_t)(b * HH + h) * SS + srow) * DD + d] = f2bf(acc[i][j][r] + bb);
            }
        }
    }
}

// ---------------- K1b: transpose V [B,H,S,D] -> [B,H,D,S] (bf16) ----------------
__global__ __launch_bounds__(256) void transpose_v_kernel(
    const u16* __restrict__ vbf, u16* __restrict__ vtg)
{
    const int s0 = blockIdx.x * 64;
    const int bh = blockIdx.y;
    __shared__ u16 t_lds[64][72];
    const int tid = threadIdx.x;
#pragma unroll
    for (int rr = 0; rr < 2; ++rr) {
        int idx = tid + rr * 256;
        int row = idx >> 3, c8 = (idx & 7) * 8;
        *reinterpret_cast<u16x8*>(&t_lds[row][c8]) =
            *reinterpret_cast<const u16x8*>(&vbf[((size_t)bh * SS + s0 + row) * DD + c8]);
    }
    __syncthreads();
#pragma unroll
    for (int rr = 0; rr < 2; ++rr) {
        int idx = tid + rr * 256;
        int d = idx >> 3, tt = (idx & 7) * 8;
        u16x8 o;
#pragma unroll
        for (int j = 0; j < 8; ++j) o[j] = t_lds[tt + j][d];
        *reinterpret_cast<u16x8*>(&vtg[((size_t)bh * DD + d) * SS + s0 + tt]) = o;
    }
}

// ---------------- K2: flash attention — R17 (kbias in LDS, vmcnt-clean loop) ----------------
__global__ __launch_bounds__(512, 4) void attn_kernel(
    const u16* __restrict__ qbf, const u16* __restrict__ kbf, const u16* __restrict__ vtg,
    const float* __restrict__ kbias, const float* __restrict__ qmask,
    u16* __restrict__ att)
{
    const int id = blockIdx.x;
    const int wg = (id & 7) * 64 + (id >> 3);   // XCD-chunked: 4 bh per XCD
    const int bh = wg >> 4, qt = wg & 15;
    const int b = bh >> 4, h = bh & 15;

    const int tid = threadIdx.x;
    const int w = tid >> 6;
    const int lane = tid & 63;
    const int ql = lane & 31, hi = lane >> 5;
    const int qw = w & 3, th = w >> 2;
    const int q0 = qt * 128 + qw * 32;

    __shared__ u16 sm[8][4096];
    __shared__ float kb_lds[2048];

    const size_t bhoff = (size_t)bh * SS * DD;
    const u16* Kb = kbf + bhoff;                    // [2048][64]
    const u16* Vb = vtg + (size_t)bh * DD * SS;     // [64][2048]

    *reinterpret_cast<float4*>(&kb_lds[tid * 4]) =
        *reinterpret_cast<const float4*>(&kbias[(size_t)b * SS + tid * 4]);

    bf16x8 aq[4];
#pragma unroll
    for (int c = 0; c < 4; ++c)
        aq[c] = *reinterpret_cast<const bf16x8*>(&qbf[bhoff + (size_t)(q0 + ql) * DD + c * 16 + hi * 8]);

    f32x16 acc0 = {}, acc1 = {};
    const f32x16 fz = {};
    float l_run = 0.f;

    const int r_ = tid >> 3;
    const int lch_ = (((tid & 7) * 16) ^ ((r_ & 7) << 4)) >> 1;

#define STAGE(bufi, t64)                                                                   \
    do {                                                                                   \
        gl_lds16(Kb + (size_t)((t64) + r_) * 64 + lch_,          &sm[0 + (bufi)][tid * 8]); \
        gl_lds16(Vb + (size_t)r_ * SS + (t64) + lch_,            &sm[2 + (bufi)][tid * 8]); \
        gl_lds16(Kb + (size_t)(1024 + (t64) + r_) * 64 + lch_,   &sm[4 + (bufi)][tid * 8]); \
        gl_lds16(Vb + (size_t)r_ * SS + 1024 + (t64) + lch_,     &sm[6 + (bufi)][tid * 8]); \
    } while (0)

    STAGE(0, 0);
    asm volatile("s_waitcnt vmcnt(0)" ::: "memory");
    __syncthreads();

    const float* kbl = kb_lds + th * 1024;
    int cur = 0;
    for (int ti = 0; ti < 16; ++ti) {
        const int t0 = ti * 64;
        if (ti < 15) STAGE(cur ^ 1, t0 + 64);

        const char* kbase = reinterpret_cast<const char*>(&sm[th * 4 + cur][0]);
        const char* vbase = reinterpret_cast<const char*>(&sm[th * 4 + 2 + cur][0]);

        float4 km0[4], km1[4];
#pragma unroll
        for (int g = 0; g < 4; ++g) {
            km0[g] = *reinterpret_cast<const float4*>(kbl + t0 + g * 8 + hi * 4);
            km1[g] = *reinterpret_cast<const float4*>(kbl + t0 + 32 + g * 8 + hi * 4);
        }

        const int row0 = ql, row1 = 32 + ql;
        const int swz0 = (row0 & 7) << 4, swz1 = (row1 & 7) << 4;
        f32x16 s0, s1;
        {
            bf16x8 kf0 = *reinterpret_cast<const bf16x8*>(kbase + row0 * 128 + ((0 * 32 + hi * 16) ^ swz0));
            bf16x8 kf1 = *reinterpret_cast<const bf16x8*>(kbase + row1 * 128 + ((0 * 32 + hi * 16) ^ swz1));
            s0 = __builtin_amdgcn_mfma_f32_32x32x16_bf16(kf0, aq[0], fz, 0, 0, 0);
            s1 = __builtin_amdgcn_mfma_f32_32x32x16_bf16(kf1, aq[0], fz, 0, 0, 0);
        }
#pragma unroll
        for (int c = 1; c < 4; ++c) {
            bf16x8 kf0 = *reinterpret_cast<const bf16x8*>(kbase + row0 * 128 + ((c * 32 + hi * 16) ^ swz0));
            bf16x8 kf1 = *reinterpret_cast<const bf16x8*>(kbase + row1 * 128 + ((c * 32 + hi * 16) ^ swz1));
            s0 = __builtin_amdgcn_mfma_f32_32x32x16_bf16(kf0, aq[c], s0, 0, 0, 0);
            s1 = __builtin_amdgcn_mfma_f32_32x32x16_bf16(kf1, aq[c], s1, 0, 0, 0);
        }

        float p0[16], p1[16];
        float ps0 = 0.f, ps1 = 0.f, ps2 = 0.f, ps3 = 0.f;
#pragma unroll
        for (int r = 0; r < 16; ++r) {
            float kv0 = (r & 1) ? ((r & 2) ? km0[r >> 2].w : km0[r >> 2].y)
                                : ((r & 2) ? km0[r >> 2].z : km0[r >> 2].x);
            float kv1 = (r & 1) ? ((r & 2) ? km1[r >> 2].w : km1[r >> 2].y)
                                : ((r & 2) ? km1[r >> 2].z : km1[r >> 2].x);
            float e0 = __builtin_amdgcn_exp2f(s0[r] + kv0);
            float e1 = __builtin_amdgcn_exp2f(s1[r] + kv1);
            p0[r] = e0; p1[r] = e1;
            if (r & 1) { ps1 += e0; ps3 += e1; } else { ps0 += e0; ps2 += e1; }
        }
        l_run += (ps0 + ps1) + (ps2 + ps3);

        bf16x8 pw[4];
#pragma unroll
        for (int hf = 0; hf < 2; ++hf) {
            {
                u32 x1 = cvt_pk_bf16(p0[hf * 8 + 0], p0[hf * 8 + 1]);
                u32 x2 = cvt_pk_bf16(p0[hf * 8 + 2], p0[hf * 8 + 3]);
                u32 y1 = cvt_pk_bf16(p0[hf * 8 + 4], p0[hf * 8 + 5]);
                u32 y2 = cvt_pk_bf16(p0[hf * 8 + 6], p0[hf * 8 + 7]);
                u32x2 sA = __builtin_amdgcn_permlane32_swap(x1, y1, false, false);
                u32x2 sB = __builtin_amdgcn_permlane32_swap(x2, y2, false, false);
                u32x4 fr; fr[0] = sA[0]; fr[1] = sB[0]; fr[2] = sA[1]; fr[3] = sB[1];
                pw[hf] = __builtin_bit_cast(bf16x8, fr);
            }
            {
                u32 x1 = cvt_pk_bf16(p1[hf * 8 + 0], p1[hf * 8 + 1]);
                u32 x2 = cvt_pk_bf16(p1[hf * 8 + 2], p1[hf * 8 + 3]);
                u32 y1 = cvt_pk_bf16(p1[hf * 8 + 4], p1[hf * 8 + 5]);
                u32 y2 = cvt_pk_bf16(p1[hf * 8 + 6], p1[hf * 8 + 7]);
                u32x2 sA = __builtin_amdgcn_permlane32_swap(x1, y1, false, false);
                u32x2 sB = __builtin_amdgcn_permlane32_swap(x2, y2, false, false);
                u32x4 fr; fr[0] = sA[0]; fr[1] = sB[0]; fr[2] = sA[1]; fr[3] = sB[1];
                pw[2 + hf] = __builtin_bit_cast(bf16x8, fr);
            }
        }

#pragma unroll
        for (int cc = 0; cc < 4; ++cc) {
            bf16x8 vf0 = *reinterpret_cast<const bf16x8*>(vbase + row0 * 128 + ((cc * 32 + hi * 16) ^ swz0));
            bf16x8 vf1 = *reinterpret_cast<const bf16x8*>(vbase + row1 * 128 + ((cc * 32 + hi * 16) ^ swz1));
            acc0 = __builtin_amdgcn_mfma_f32_32x32x16_bf16(vf0, pw[cc], acc0, 0, 0, 0);
            acc1 = __builtin_amdgcn_mfma_f32_32x32x16_bf16(vf1, pw[cc], acc1, 0, 0, 0);
        }

        asm volatile("s_waitcnt vmcnt(0)" ::: "memory");
        __syncthreads();
        cur ^= 1;
    }
#undef STAGE

    float* cb = reinterpret_cast<float*>(&sm[0][0]);
    const int ci = (qw * 64 + lane) * 34;
    if (th == 1) {
#pragma unroll
        for (int r = 0; r < 16; ++r) { cb[ci + r] = acc0[r]; cb[ci + 16 + r] = acc1[r]; }
        cb[ci + 32] = l_run;
    }
    __syncthreads();
    if (th == 0) {
#pragma unroll
        for (int r = 0; r < 16; ++r) { acc0[r] += cb[ci + r]; acc1[r] += cb[ci + 16 + r]; }
        l_run += cb[ci + 32];

        float l1 = l_run + __shfl_xor(l_run, 32);
        float qm = qmask[(size_t)b * SS + q0 + ql];
        float inv = (l1 > 0.f && qm != 0.f) ? 1.f / l1 : 0.f;
        u16* orow = att + ((size_t)b * SS + q0 + ql) * 1024 + h * 64;
#pragma unroll
        for (int c = 0; c < 4; ++c)
#pragma unroll
            for (int pp = 0; pp < 2; ++pp) {
                int d0 = 8 * c + 4 * hi + 2 * pp;
                u32 w0 = cvt_pk_bf16(acc0[4 * c + 2 * pp] * inv, acc0[4 * c + 2 * pp + 1] * inv);
                u32 w1 = cvt_pk_bf16(acc1[4 * c + 2 * pp] * inv, acc1[4 * c + 2 * pp + 1] * inv);
                *reinterpret_cast<u32*>(orow + d0) = w0;
                *reinterpret_cast<u32*>(orow + 32 + d0) = w1;
            }
    }
}

// ---------------- K3: final GEMM — 512 threads (8 waves), counted-vmcnt depth-2 pipeline ----------------
__global__ __launch_bounds__(512, 2) void gemm_final_kernel(
    const u16* __restrict__ A, const u16* __restrict__ BT,
    const float* __restrict__ b2, float* __restrict__ out)
{
    const int id = blockIdx.x;
    const int xcd = id & 7, idx = id >> 3;       // idx 0..31
    const int p = xcd * 4 + (idx >> 3);          // m-panel 0..31
    const int m0 = p * 128;
    const int n0 = (idx & 7) * 128;

    __shared__ u16 a_lds[3][128][64];
    __shared__ u16 b_lds[3][128][64];

    const int tid = threadIdx.x;
    const int lane = tid & 63;
    const int w = tid >> 6;              // 8 waves
    const int wm = w >> 1, wn = w & 1;   // wave tile: 32 rows x 64 cols
    const int lrow = lane & 15;
    const int lgrp = lane >> 4;

    f32x4 acc[2][4] = {};

#define STAGEF(bufi, k0s)                                                                  \
    do {                                                                                   \
        _Pragma("unroll")                                                                  \
        for (int it = 0; it < 2; ++it) {                                                   \
            int s_ = tid + it * 512;                                                       \
            int row_ = s_ >> 3;                                                            \
            int sc_ = ((((s_ & 7) * 16) ^ ((row_ & 7) << 4)) >> 1);                        \
            gl_lds16(&A[(size_t)(m0 + row_) * 1024 + (k0s) + sc_], &a_lds[bufi][0][0] + s_ * 8);  \
            gl_lds16(&BT[(size_t)(n0 + row_) * 1024 + (k0s) + sc_], &b_lds[bufi][0][0] + s_ * 8); \
        }                                                                                  \
    } while (0)

#define COMPUTEF(bufi)                                                                     \
    do {                                                                                   \
        const char* ab_ = reinterpret_cast<const char*>(&a_lds[bufi][0][0]);               \
        const char* bb_ = reinterpret_cast<const char*>(&b_lds[bufi][0][0]);               \
        _Pragma("unroll")                                                                  \
        for (int kk = 0; kk < 2; ++kk) {                                                   \
            bf16x8 af[2], bfr[4];                                                          \
            _Pragma("unroll")                                                              \
            for (int i = 0; i < 2; ++i) {                                                  \
                int row = wm * 32 + i * 16 + lrow;                                         \
                af[i] = *reinterpret_cast<const bf16x8*>(ab_ + row * 128 + ((kk * 64 + lgrp * 16) ^ ((row & 7) << 4))); \
            }                                                                              \
            _Pragma("unroll")                                                              \
            for (int j = 0; j < 4; ++j) {                                                  \
                int row = wn * 64 + j * 16 + lrow;                                         \
                bfr[j] = *reinterpret_cast<const bf16x8*>(bb_ + row * 128 + ((kk * 64 + lgrp * 16) ^ ((row & 7) << 4))); \
            }                                                                              \
            _Pragma("unroll")                                                              \
            for (int i = 0; i < 2; ++i)                                                    \
                _Pragma("unroll")                                                          \
                for (int j = 0; j < 4; ++j)                                                \
                    acc[i][j] = __builtin_amdgcn_mfma_f32_16x16x32_bf16(af[i], bfr[j], acc[i][j], 0, 0, 0); \
        }                                                                                  \
    } while (0)

    STAGEF(0, 0);
    STAGEF(1, 64);
    asm volatile("s_waitcnt vmcnt(4)" ::: "memory");
    __builtin_amdgcn_s_barrier();

#pragma unroll
    for (int t = 0; t < 16; ++t) {
        if (t < 14) STAGEF((t + 2) % 3, (t + 2) * 64);

        COMPUTEF(t % 3);

        if (t < 14)       asm volatile("s_waitcnt vmcnt(4)" ::: "memory");
        else if (t == 14) asm volatile("s_waitcnt vmcnt(0)" ::: "memory");
        if (t < 15) __builtin_amdgcn_s_barrier();
    }
#undef STAGEF
#undef COMPUTEF

#pragma unroll
    for (int i = 0; i < 2; ++i) {
#pragma unroll
        for (int j = 0; j < 4; ++j) {
            int n = n0 + wn * 64 + j * 16 + lrow;
            float bb = b2[n];
#pragma unroll
            for (int r = 0; r < 4; ++r) {
                int m = m0 + wm * 32 + i * 16 + lgrp * 4 + r;
                out[(size_t)m * 1024 + n] = acc[i][j][r] + bb;
            }
        }
    }
}

extern "C" void kernel_launch(void* const* d_in, const int* in_sizes, int n_in,
                              void* d_out, int out_size, void* d_ws, size_t ws_size,
                              hipStream_t stream) {
    const float* query = (const float*)d_in[0];
    const float* key   = (const float*)d_in[1];
    const float* value = (const float*)d_in[2];
    const float* qmask = (const float*)d_in[3];
    const float* kmask = (const float*)d_in[4];
    const float* Wq = (const float*)d_in[5];
    const float* bq = (const float*)d_in[6];
    const float* Wk = (const float*)d_in[7];
    const float* bk = (const float*)d_in[8];
    const float* Wv = (const float*)d_in[9];
    const float* bv = (const float*)d_in[10];
    const float* Wo = (const float*)d_in[11];
    const float* bo = (const float*)d_in[12];
    const float* Wf = (const float*)d_in[13];
    const float* bfin = (const float*)d_in[14];
    float* out = (float*)d_out;

    char* ws = (char*)d_ws;
    u16*   WT  = (u16*)  (ws + 0);          // 6291456
    u16*   W2T = (u16*)  (ws + 6291456);    // 2097152
    float* b2  = (float*)(ws + 8388608);    // 4096
    u16*   qbf = (u16*)  (ws + 8392704);    // 8388608
    u16*   kbf = (u16*)  (ws + 16781312);   // 8388608
    u16*   vbf = (u16*)  (ws + 25169920);   // 8388608
    u16*   att = (u16*)  (ws + 33558528);   // 8388608
    u16*   vtg = (u16*)  (ws + 41947136);   // 8388608
    float* kb  = (float*)(ws + 50335744);   // 16384  (end ~50.4 MB)

    hipMemsetAsync(b2, 0, 1024 * sizeof(float), stream);
    transpose_w_kernel<<<dim3(16, 16, 3), 256, 0, stream>>>(Wq, Wk, Wv, WT);
    build_w2t_kernel<<<dim3(16, 16), 256, 0, stream>>>(Wo, bo, Wf, bfin, W2T, b2);
    kbias_kernel<<<dim3(16), 256, 0, stream>>>(kmask, kb);
    gemm_qkv_kernel<<<dim3(768), 512, 0, stream>>>(query, key, value, WT, bq, bk, bv, qbf, kbf, vbf);
    transpose_v_kernel<<<dim3(32, 32), 256, 0, stream>>>(vbf, vtg);
    attn_kernel<<<dim3(512), 512, 0, stream>>>(qbf, kbf, vtg, kb, qmask, att);
    gemm_final_kernel<<<dim3(256), 512, 0, stream>>>(att, W2T, b2, out);
}

// Round 20
// 129.284 us; speedup vs baseline: 1.0827x; 1.0148x over previous
//
#include <hip/hip_runtime.h>

typedef unsigned short u16;
typedef unsigned int u32;
typedef __bf16 bf16x8 __attribute__((ext_vector_type(8)));
typedef float f32x4 __attribute__((ext_vector_type(4)));
typedef float f32x16 __attribute__((ext_vector_type(16)));
typedef unsigned short u16x4 __attribute__((ext_vector_type(4)));
typedef unsigned short u16x8 __attribute__((ext_vector_type(8)));
typedef unsigned int u32x2 __attribute__((ext_vector_type(2)));
typedef unsigned int u32x4 __attribute__((ext_vector_type(4)));

#define BB 2
#define SS 2048
#define EE 1024
#define HH 16
#define DD 64

#define QSCALE_F 0.18033688011112042f  /* (1/sqrt(64)) * log2(e) */
#define MSHIFT   12.0f

static __device__ inline u16 f2bf(float f) {
    union { float f; unsigned int u; } v; v.f = f;
    unsigned int u = v.u;
    unsigned int r = (u + 0x7FFFu + ((u >> 16) & 1u)) >> 16;  // RNE
    return (u16)r;
}

static __device__ inline u32 cvt_pk_bf16(float lo, float hi) {
    u32 r;
    asm volatile("v_cvt_pk_bf16_f32 %0, %1, %2" : "=v"(r) : "v"(lo), "v"(hi));
    return r;
}

static __device__ __forceinline__ void gl_lds16(const u16* g, u16* l) {
    __builtin_amdgcn_global_load_lds(
        (const __attribute__((address_space(1))) void*)g,
        (__attribute__((address_space(3))) void*)l, 16, 0, 0);
}

// ---------------- K0a: transpose Wq/Wk/Wv [H,E,D] f32 -> WT [3*1024][1024] bf16 ----------------
__global__ __launch_bounds__(256) void transpose_w_kernel(
    const float* __restrict__ Wq, const float* __restrict__ Wk, const float* __restrict__ Wv,
    u16* __restrict__ WT)
{
    const int z = blockIdx.z;
    const int h = blockIdx.y;
    const int e0 = blockIdx.x * 64;
    const float* W = (z == 0) ? Wq : (z == 1) ? Wk : Wv;
    const float sc = (z == 0) ? QSCALE_F : 1.0f;
    __shared__ float t_lds[64][68];
    const int tid = threadIdx.x;
#pragma unroll
    for (int it = 0; it < 4; ++it) {
        int s = tid + it * 256;
        int i = s >> 4, d4 = (s & 15) * 4;
        const float4 v = *reinterpret_cast<const float4*>(&W[((size_t)h * EE + e0 + i) * DD + d4]);
        t_lds[i][d4 + 0] = v.x; t_lds[i][d4 + 1] = v.y;
        t_lds[i][d4 + 2] = v.z; t_lds[i][d4 + 3] = v.w;
    }
    __syncthreads();
#pragma unroll
    for (int it = 0; it < 4; ++it) {
        int s = tid + it * 256;
        int d = s >> 4, i4 = (s & 15) * 4;
        u16x4 o;
        o[0] = f2bf(t_lds[i4 + 0][d] * sc); o[1] = f2bf(t_lds[i4 + 1][d] * sc);
        o[2] = f2bf(t_lds[i4 + 2][d] * sc); o[3] = f2bf(t_lds[i4 + 3][d] * sc);
        *reinterpret_cast<u16x4*>(&WT[((size_t)z * 1024 + h * 64 + d) * EE + e0 + i4]) = o;
    }
}

// ---------------- K0b: W2T[e][h*D+d] = sum_o Wo[h,d,o]*Wf[h*O+o,e]; b2 ----------------
__global__ __launch_bounds__(256) void build_w2t_kernel(
    const float* __restrict__ Wo, const float* __restrict__ bo,
    const float* __restrict__ Wf, const float* __restrict__ bfin,
    u16* __restrict__ W2T, float* __restrict__ b2)
{
    const int h = blockIdx.y;
    const int e0 = blockIdx.x * 64;
    __shared__ float wo_lds[64][65];  // [d][o]
    __shared__ float wf_lds[64][65];  // [o][i]
    const int tid = threadIdx.x;
#pragma unroll
    for (int it = 0; it < 4; ++it) {
        int s = tid + it * 256;
        int r = s >> 4, c4 = (s & 15) * 4;
        const float4 a = *reinterpret_cast<const float4*>(&Wo[((size_t)h * 64 + r) * 64 + c4]);
        wo_lds[r][c4 + 0] = a.x; wo_lds[r][c4 + 1] = a.y; wo_lds[r][c4 + 2] = a.z; wo_lds[r][c4 + 3] = a.w;
        const float4 b = *reinterpret_cast<const float4*>(&Wf[((size_t)(h * 64 + r)) * EE + e0 + c4]);
        wf_lds[r][c4 + 0] = b.x; wf_lds[r][c4 + 1] = b.y; wf_lds[r][c4 + 2] = b.z; wf_lds[r][c4 + 3] = b.w;
    }
    __syncthreads();
    const int d = tid & 63;
    const int i0 = (tid >> 6) * 16;
#pragma unroll
    for (int ii = 0; ii < 16; ++ii) {
        int i = i0 + ii;
        float acc = 0.f;
#pragma unroll 8
        for (int o = 0; o < 64; ++o) acc += wo_lds[d][o] * wf_lds[o][i];
        W2T[((size_t)(e0 + i)) * 1024 + h * 64 + d] = f2bf(acc);
    }
    if (tid < 64) {
        int i = tid;
        float acc = 0.f;
        for (int o = 0; o < 64; ++o) acc += bo[h * 64 + o] * wf_lds[o][i];
        if (h == 0) acc += bfin[e0 + i];
        atomicAdd(&b2[e0 + i], acc);
    }
}

// ---------------- K0c: kbias[b][t] = kmask ? -MSHIFT : -1e38 ----------------
__global__ __launch_bounds__(256) void kbias_kernel(const float* __restrict__ km, float* __restrict__ kb)
{
    int i = blockIdx.x * 256 + threadIdx.x;
    if (i < BB * SS) kb[i] = (km[i] != 0.f) ? -MSHIFT : -1e38f;
}

// ---------------- K1: QKV GEMM — 512 threads, counted-vmcnt depth-2; z==2 writes V^T directly ----------------
__global__ __launch_bounds__(512, 4) void gemm_qkv_kernel(
    const float* __restrict__ query, const float* __restrict__ key, const float* __restrict__ value,
    const u16* __restrict__ WT,
    const float* __restrict__ bq, const float* __restrict__ bk, const float* __restrict__ bv,
    u16* __restrict__ qbf, u16* __restrict__ kbf, u16* __restrict__ vtg)
{
    const int id = blockIdx.x;
    const int xcd = id & 7, idx = id >> 3;       // idx 0..95
    const int p = xcd * 12 + (idx >> 3);         // panel 0..95
    const int z = p >> 5;
    const int m0 = (p & 31) * 128;
    const int n0 = (idx & 7) * 128;

    const float* A   = (z == 0) ? query : (z == 1) ? key : value;
    const float* bia = (z == 0) ? bq    : (z == 1) ? bk  : bv;
    const float bsc  = (z == 0) ? QSCALE_F : 1.0f;
    const u16* BT = WT + (size_t)z * 1024 * 1024;

    __shared__ u16 a_lds[2][128][64];   // 32 KB, swizzled content
    __shared__ u16 b_lds[3][128][64];   // 48 KB

    const int tid = threadIdx.x;
    const int lane = tid & 63;
    const int w = tid >> 6;              // 8 waves
    const int wm = w >> 1, wn = w & 1;   // wave tile: 32 rows x 64 cols
    const int lrow = lane & 15;
    const int lgrp = lane >> 4;

    f32x4 acc[2][4] = {};
    float4 ar0[4], ar1[4];

#define LOADA(ar, k0s)                                                                     \
    do {                                                                                   \
        _Pragma("unroll")                                                                  \
        for (int it = 0; it < 4; ++it) {                                                   \
            int s_ = tid + it * 512;                                                       \
            int row_ = s_ >> 4, c4_ = (s_ & 15) * 4;                                       \
            ar[it] = *reinterpret_cast<const float4*>(&A[(size_t)(m0 + row_) * 1024 + (k0s) + c4_]); \
        }                                                                                  \
    } while (0)

#define STAGEB(bufi, k0s)                                                                  \
    do {                                                                                   \
        _Pragma("unroll")                                                                  \
        for (int it = 0; it < 2; ++it) {                                                   \
            int s_ = tid + it * 512;                                                       \
            int row_ = s_ >> 3;                                                            \
            int sc_ = ((((s_ & 7) * 16) ^ ((row_ & 7) << 4)) >> 1);                        \
            gl_lds16(&BT[(size_t)(n0 + row_) * 1024 + (k0s) + sc_], &b_lds[bufi][0][0] + s_ * 8); \
        }                                                                                  \
    } while (0)

#define WRITEA(bufi, ar)                                                                   \
    do {                                                                                   \
        _Pragma("unroll")                                                                  \
        for (int it = 0; it < 4; ++it) {                                                   \
            int s_ = tid + it * 512;                                                       \
            int row_ = s_ >> 4, c8_ = (s_ & 15) * 8;                                       \
            u32x2 o_;                                                                      \
            o_[0] = cvt_pk_bf16(ar[it].x, ar[it].y);                                       \
            o_[1] = cvt_pk_bf16(ar[it].z, ar[it].w);                                       \
            *reinterpret_cast<u32x2*>(reinterpret_cast<char*>(&a_lds[bufi][0][0]) + row_ * 128 + (c8_ ^ ((row_ & 7) << 4))) = o_; \
        }                                                                                  \
    } while (0)

#define COMPUTE(abuf, bbuf)                                                                \
    do {                                                                                   \
        const char* ab_ = reinterpret_cast<const char*>(&a_lds[abuf][0][0]);               \
        const char* bb_ = reinterpret_cast<const char*>(&b_lds[bbuf][0][0]);               \
        _Pragma("unroll")                                                                  \
        for (int kk = 0; kk < 2; ++kk) {                                                   \
            bf16x8 af[2], bfr[4];                                                          \
            _Pragma("unroll")                                                              \
            for (int i = 0; i < 2; ++i) {                                                  \
                int row = wm * 32 + i * 16 + lrow;                                         \
                af[i] = *reinterpret_cast<const bf16x8*>(ab_ + row * 128 + ((kk * 64 + lgrp * 16) ^ ((row & 7) << 4))); \
            }                                                                              \
            _Pragma("unroll")                                                              \
            for (int j = 0; j < 4; ++j) {                                                  \
                int row = wn * 64 + j * 16 + lrow;                                         \
                bfr[j] = *reinterpret_cast<const bf16x8*>(bb_ + row * 128 + ((kk * 64 + lgrp * 16) ^ ((row & 7) << 4))); \
            }                                                                              \
            _Pragma("unroll")                                                              \
            for (int i = 0; i < 2; ++i)                                                    \
                _Pragma("unroll")                                                          \
                for (int j = 0; j < 4; ++j)                                                \
                    acc[i][j] = __builtin_amdgcn_mfma_f32_16x16x32_bf16(af[i], bfr[j], acc[i][j], 0, 0, 0); \
        }                                                                                  \
    } while (0)

    // prologue: tiles 0 and 1 in flight (12 VMEM/thread); wait first 6 -> tile 0 ready
    LOADA(ar0, 0);
    STAGEB(0, 0);
    LOADA(ar1, 64);
    STAGEB(1, 64);
    asm volatile("s_waitcnt vmcnt(6)" ::: "memory");
    WRITEA(0, ar0);
    asm volatile("s_waitcnt lgkmcnt(0)" ::: "memory");
    __builtin_amdgcn_s_barrier();

#pragma unroll
    for (int t = 0; t < 16; ++t) {
        if (t < 14) {
            if ((t & 1) == 0) LOADA(ar0, (t + 2) * 64);
            else              LOADA(ar1, (t + 2) * 64);
            STAGEB((t + 2) % 3, (t + 2) * 64);
        }

        COMPUTE(t & 1, t % 3);

        if (t < 14)      asm volatile("s_waitcnt vmcnt(6)" ::: "memory");
        else if (t == 14) asm volatile("s_waitcnt vmcnt(0)" ::: "memory");
        if (t < 15) {
            if ((t & 1) == 0) WRITEA(1, ar1);
            else              WRITEA(0, ar0);
            asm volatile("s_waitcnt lgkmcnt(0)" ::: "memory");
            __builtin_amdgcn_s_barrier();
        }
    }
#undef LOADA
#undef STAGEB
#undef WRITEA
#undef COMPUTE

    if (z == 2) {
        // V written pre-transposed: vtg[((b*HH+h)*DD+d)*SS + srow], 4 consecutive srow -> one 8B store.
        // Tile rows never straddle the S=2048 batch boundary (2048 % 128 == 0).
#pragma unroll
        for (int i = 0; i < 2; ++i) {
#pragma unroll
            for (int j = 0; j < 4; ++j) {
                int n = n0 + wn * 64 + j * 16 + lrow;
                int h = n >> 6, d = n & 63;
                float bb = bia[n];
                int m = m0 + wm * 32 + i * 16 + lgrp * 4;
                int b = m >> 11, srow = m & 2047;
                u16x4 o;
#pragma unroll
                for (int r = 0; r < 4; ++r) o[r] = f2bf(acc[i][j][r] + bb);
                *reinterpret_cast<u16x4*>(&vtg[((size_t)(b * HH + h) * DD + d) * SS + srow]) = o;
            }
        }
    } else {
        u16* outp = (z == 0) ? qbf : kbf;
#pragma unroll
        for (int i = 0; i < 2; ++i) {
#pragma unroll
            for (int j = 0; j < 4; ++j) {
                int n = n0 + wn * 64 + j * 16 + lrow;
                int h = n >> 6, d = n & 63;
                float bb = bia[n] * bsc;
#pragma unroll
                for (int r = 0; r < 4; ++r) {
                    int m = m0 + wm * 32 + i * 16 + lgrp * 4 + r;
                    int b = m >> 11, srow = m & 2047;
                    outp[((size_t)(b * HH + h) * SS + srow) * DD + d] = f2bf(acc[i][j][r] + bb);
                }
            }
        }
    }
}

// ---------------- K2: flash attention — R17 (kbias in LDS, vmcnt-clean loop) ----------------
__global__ __launch_bounds__(512, 4) void attn_kernel(
    const u16* __restrict__ qbf, const u16* __restrict__ kbf, const u16* __restrict__ vtg,
    const float* __restrict__ kbias, const float* __restrict__ qmask,
    u16* __restrict__ att)
{
    const int id = blockIdx.x;
    const int wg = (id & 7) * 64 + (id >> 3);   // XCD-chunked: 4 bh per XCD
    const int bh = wg >> 4, qt = wg & 15;
    const int b = bh >> 4, h = bh & 15;

    const int tid = threadIdx.x;
    const int w = tid >> 6;
    const int lane = tid & 63;
    const int ql = lane & 31, hi = lane >> 5;
    const int qw = w & 3, th = w >> 2;
    const int q0 = qt * 128 + qw * 32;

    __shared__ u16 sm[8][4096];
    __shared__ float kb_lds[2048];

    const size_t bhoff = (size_t)bh * SS * DD;
    const u16* Kb = kbf + bhoff;                    // [2048][64]
    const u16* Vb = vtg + (size_t)bh * DD * SS;     // [64][2048]

    *reinterpret_cast<float4*>(&kb_lds[tid * 4]) =
        *reinterpret_cast<const float4*>(&kbias[(size_t)b * SS + tid * 4]);

    bf16x8 aq[4];
#pragma unroll
    for (int c = 0; c < 4; ++c)
        aq[c] = *reinterpret_cast<const bf16x8*>(&qbf[bhoff + (size_t)(q0 + ql) * DD + c * 16 + hi * 8]);

    f32x16 acc0 = {}, acc1 = {};
    const f32x16 fz = {};
    float l_run = 0.f;

    const int r_ = tid >> 3;
    const int lch_ = (((tid & 7) * 16) ^ ((r_ & 7) << 4)) >> 1;

#define STAGE(bufi, t64)                                                                   \
    do {                                                                                   \
        gl_lds16(Kb + (size_t)((t64) + r_) * 64 + lch_,          &sm[0 + (bufi)][tid * 8]); \
        gl_lds16(Vb + (size_t)r_ * SS + (t64) + lch_,            &sm[2 + (bufi)][tid * 8]); \
        gl_lds16(Kb + (size_t)(1024 + (t64) + r_) * 64 + lch_,   &sm[4 + (bufi)][tid * 8]); \
        gl_lds16(Vb + (size_t)r_ * SS + 1024 + (t64) + lch_,     &sm[6 + (bufi)][tid * 8]); \
    } while (0)

    STAGE(0, 0);
    asm volatile("s_waitcnt vmcnt(0)" ::: "memory");
    __syncthreads();

    const float* kbl = kb_lds + th * 1024;
    int cur = 0;
    for (int ti = 0; ti < 16; ++ti) {
        const int t0 = ti * 64;
        if (ti < 15) STAGE(cur ^ 1, t0 + 64);

        const char* kbase = reinterpret_cast<const char*>(&sm[th * 4 + cur][0]);
        const char* vbase = reinterpret_cast<const char*>(&sm[th * 4 + 2 + cur][0]);

        float4 km0[4], km1[4];
#pragma unroll
        for (int g = 0; g < 4; ++g) {
            km0[g] = *reinterpret_cast<const float4*>(kbl + t0 + g * 8 + hi * 4);
            km1[g] = *reinterpret_cast<const float4*>(kbl + t0 + 32 + g * 8 + hi * 4);
        }

        const int row0 = ql, row1 = 32 + ql;
        const int swz0 = (row0 & 7) << 4, swz1 = (row1 & 7) << 4;
        f32x16 s0, s1;
        {
            bf16x8 kf0 = *reinterpret_cast<const bf16x8*>(kbase + row0 * 128 + ((0 * 32 + hi * 16) ^ swz0));
            bf16x8 kf1 = *reinterpret_cast<const bf16x8*>(kbase + row1 * 128 + ((0 * 32 + hi * 16) ^ swz1));
            s0 = __builtin_amdgcn_mfma_f32_32x32x16_bf16(kf0, aq[0], fz, 0, 0, 0);
            s1 = __builtin_amdgcn_mfma_f32_32x32x16_bf16(kf1, aq[0], fz, 0, 0, 0);
        }
#pragma unroll
        for (int c = 1; c < 4; ++c) {
            bf16x8 kf0 = *reinterpret_cast<const bf16x8*>(kbase + row0 * 128 + ((c * 32 + hi * 16) ^ swz0));
            bf16x8 kf1 = *reinterpret_cast<const bf16x8*>(kbase + row1 * 128 + ((c * 32 + hi * 16) ^ swz1));
            s0 = __builtin_amdgcn_mfma_f32_32x32x16_bf16(kf0, aq[c], s0, 0, 0, 0);
            s1 = __builtin_amdgcn_mfma_f32_32x32x16_bf16(kf1, aq[c], s1, 0, 0, 0);
        }

        float p0[16], p1[16];
        float ps0 = 0.f, ps1 = 0.f, ps2 = 0.f, ps3 = 0.f;
#pragma unroll
        for (int r = 0; r < 16; ++r) {
            float kv0 = (r & 1) ? ((r & 2) ? km0[r >> 2].w : km0[r >> 2].y)
                                : ((r & 2) ? km0[r >> 2].z : km0[r >> 2].x);
            float kv1 = (r & 1) ? ((r & 2) ? km1[r >> 2].w : km1[r >> 2].y)
                                : ((r & 2) ? km1[r >> 2].z : km1[r >> 2].x);
            float e0 = __builtin_amdgcn_exp2f(s0[r] + kv0);
            float e1 = __builtin_amdgcn_exp2f(s1[r] + kv1);
            p0[r] = e0; p1[r] = e1;
            if (r & 1) { ps1 += e0; ps3 += e1; } else { ps0 += e0; ps2 += e1; }
        }
        l_run += (ps0 + ps1) + (ps2 + ps3);

        bf16x8 pw[4];
#pragma unroll
        for (int hf = 0; hf < 2; ++hf) {
            {
                u32 x1 = cvt_pk_bf16(p0[hf * 8 + 0], p0[hf * 8 + 1]);
                u32 x2 = cvt_pk_bf16(p0[hf * 8 + 2], p0[hf * 8 + 3]);
                u32 y1 = cvt_pk_bf16(p0[hf * 8 + 4], p0[hf * 8 + 5]);
                u32 y2 = cvt_pk_bf16(p0[hf * 8 + 6], p0[hf * 8 + 7]);
                u32x2 sA = __builtin_amdgcn_permlane32_swap(x1, y1, false, false);
                u32x2 sB = __builtin_amdgcn_permlane32_swap(x2, y2, false, false);
                u32x4 fr; fr[0] = sA[0]; fr[1] = sB[0]; fr[2] = sA[1]; fr[3] = sB[1];
                pw[hf] = __builtin_bit_cast(bf16x8, fr);
            }
            {
                u32 x1 = cvt_pk_bf16(p1[hf * 8 + 0], p1[hf * 8 + 1]);
                u32 x2 = cvt_pk_bf16(p1[hf * 8 + 2], p1[hf * 8 + 3]);
                u32 y1 = cvt_pk_bf16(p1[hf * 8 + 4], p1[hf * 8 + 5]);
                u32 y2 = cvt_pk_bf16(p1[hf * 8 + 6], p1[hf * 8 + 7]);
                u32x2 sA = __builtin_amdgcn_permlane32_swap(x1, y1, false, false);
                u32x2 sB = __builtin_amdgcn_permlane32_swap(x2, y2, false, false);
                u32x4 fr; fr[0] = sA[0]; fr[1] = sB[0]; fr[2] = sA[1]; fr[3] = sB[1];
                pw[2 + hf] = __builtin_bit_cast(bf16x8, fr);
            }
        }

#pragma unroll
        for (int cc = 0; cc < 4; ++cc) {
            bf16x8 vf0 = *reinterpret_cast<const bf16x8*>(vbase + row0 * 128 + ((cc * 32 + hi * 16) ^ swz0));
            bf16x8 vf1 = *reinterpret_cast<const bf16x8*>(vbase + row1 * 128 + ((cc * 32 + hi * 16) ^ swz1));
            acc0 = __builtin_amdgcn_mfma_f32_32x32x16_bf16(vf0, pw[cc], acc0, 0, 0, 0);
            acc1 = __builtin_amdgcn_mfma_f32_32x32x16_bf16(vf1, pw[cc], acc1, 0, 0, 0);
        }

        asm volatile("s_waitcnt vmcnt(0)" ::: "memory");
        __syncthreads();
        cur ^= 1;
    }
#undef STAGE

    float* cb = reinterpret_cast<float*>(&sm[0][0]);
    const int ci = (qw * 64 + lane) * 34;
    if (th == 1) {
#pragma unroll
        for (int r = 0; r < 16; ++r) { cb[ci + r] = acc0[r]; cb[ci + 16 + r] = acc1[r]; }
        cb[ci + 32] = l_run;
    }
    __syncthreads();
    if (th == 0) {
#pragma unroll
        for (int r = 0; r < 16; ++r) { acc0[r] += cb[ci + r]; acc1[r] += cb[ci + 16 + r]; }
        l_run += cb[ci + 32];

        float l1 = l_run + __shfl_xor(l_run, 32);
        float qm = qmask[(size_t)b * SS + q0 + ql];
        float inv = (l1 > 0.f && qm != 0.f) ? 1.f / l1 : 0.f;
        u16* orow = att + ((size_t)b * SS + q0 + ql) * 1024 + h * 64;
#pragma unroll
        for (int c = 0; c < 4; ++c)
#pragma unroll
            for (int pp = 0; pp < 2; ++pp) {
                int d0 = 8 * c + 4 * hi + 2 * pp;
                u32 w0 = cvt_pk_bf16(acc0[4 * c + 2 * pp] * inv, acc0[4 * c + 2 * pp + 1] * inv);
                u32 w1 = cvt_pk_bf16(acc1[4 * c + 2 * pp] * inv, acc1[4 * c + 2 * pp + 1] * inv);
                *reinterpret_cast<u32*>(orow + d0) = w0;
                *reinterpret_cast<u32*>(orow + 32 + d0) = w1;
            }
    }
}

// ---------------- K3: final GEMM — 512 threads (8 waves), counted-vmcnt depth-2 pipeline ----------------
__global__ __launch_bounds__(512, 2) void gemm_final_kernel(
    const u16* __restrict__ A, const u16* __restrict__ BT,
    const float* __restrict__ b2, float* __restrict__ out)
{
    const int id = blockIdx.x;
    const int xcd = id & 7, idx = id >> 3;       // idx 0..31
    const int p = xcd * 4 + (idx >> 3);          // m-panel 0..31
    const int m0 = p * 128;
    const int n0 = (idx & 7) * 128;

    __shared__ u16 a_lds[3][128][64];
    __shared__ u16 b_lds[3][128][64];

    const int tid = threadIdx.x;
    const int lane = tid & 63;
    const int w = tid >> 6;              // 8 waves
    const int wm = w >> 1, wn = w & 1;   // wave tile: 32 rows x 64 cols
    const int lrow = lane & 15;
    const int lgrp = lane >> 4;

    f32x4 acc[2][4] = {};

#define STAGEF(bufi, k0s)                                                                  \
    do {                                                                                   \
        _Pragma("unroll")                                                                  \
        for (int it = 0; it < 2; ++it) {                                                   \
            int s_ = tid + it * 512;                                                       \
            int row_ = s_ >> 3;                                                            \
            int sc_ = ((((s_ & 7) * 16) ^ ((row_ & 7) << 4)) >> 1);                        \
            gl_lds16(&A[(size_t)(m0 + row_) * 1024 + (k0s) + sc_], &a_lds[bufi][0][0] + s_ * 8);  \
            gl_lds16(&BT[(size_t)(n0 + row_) * 1024 + (k0s) + sc_], &b_lds[bufi][0][0] + s_ * 8); \
        }                                                                                  \
    } while (0)

#define COMPUTEF(bufi)                                                                     \
    do {                                                                                   \
        const char* ab_ = reinterpret_cast<const char*>(&a_lds[bufi][0][0]);               \
        const char* bb_ = reinterpret_cast<const char*>(&b_lds[bufi][0][0]);               \
        _Pragma("unroll")                                                                  \
        for (int kk = 0; kk < 2; ++kk) {                                                   \
            bf16x8 af[2], bfr[4];                                                          \
            _Pragma("unroll")                                                              \
            for (int i = 0; i < 2; ++i) {                                                  \
                int row = wm * 32 + i * 16 + lrow;                                         \
                af[i] = *reinterpret_cast<const bf16x8*>(ab_ + row * 128 + ((kk * 64 + lgrp * 16) ^ ((row & 7) << 4))); \
            }                                                                              \
            _Pragma("unroll")                                                              \
            for (int j = 0; j < 4; ++j) {                                                  \
                int row = wn * 64 + j * 16 + lrow;                                         \
                bfr[j] = *reinterpret_cast<const bf16x8*>(bb_ + row * 128 + ((kk * 64 + lgrp * 16) ^ ((row & 7) << 4))); \
            }                                                                              \
            _Pragma("unroll")                                                              \
            for (int i = 0; i < 2; ++i)                                                    \
                _Pragma("unroll")                                                          \
                for (int j = 0; j < 4; ++j)                                                \
                    acc[i][j] = __builtin_amdgcn_mfma_f32_16x16x32_bf16(af[i], bfr[j], acc[i][j], 0, 0, 0); \
        }                                                                                  \
    } while (0)

    STAGEF(0, 0);
    STAGEF(1, 64);
    asm volatile("s_waitcnt vmcnt(4)" ::: "memory");
    __builtin_amdgcn_s_barrier();

#pragma unroll
    for (int t = 0; t < 16; ++t) {
        if (t < 14) STAGEF((t + 2) % 3, (t + 2) * 64);

        COMPUTEF(t % 3);

        if (t < 14)       asm volatile("s_waitcnt vmcnt(4)" ::: "memory");
        else if (t == 14) asm volatile("s_waitcnt vmcnt(0)" ::: "memory");
        if (t < 15) __builtin_amdgcn_s_barrier();
    }
#undef STAGEF
#undef COMPUTEF

#pragma unroll
    for (int i = 0; i < 2; ++i) {
#pragma unroll
        for (int j = 0; j < 4; ++j) {
            int n = n0 + wn * 64 + j * 16 + lrow;
            float bb = b2[n];
#pragma unroll
            for (int r = 0; r < 4; ++r) {
                int m = m0 + wm * 32 + i * 16 + lgrp * 4 + r;
                out[(size_t)m * 1024 + n] = acc[i][j][r] + bb;
            }
        }
    }
}

extern "C" void kernel_launch(void* const* d_in, const int* in_sizes, int n_in,
                              void* d_out, int out_size, void* d_ws, size_t ws_size,
                              hipStream_t stream) {
    const float* query = (const float*)d_in[0];
    const float* key   = (const float*)d_in[1];
    const float* value = (const float*)d_in[2];
    const float* qmask = (const float*)d_in[3];
    const float* kmask = (const float*)d_in[4];
    const float* Wq = (const float*)d_in[5];
    const float* bq = (const float*)d_in[6];
    const float* Wk = (const float*)d_in[7];
    const float* bk = (const float*)d_in[8];
    const float* Wv = (const float*)d_in[9];
    const float* bv = (const float*)d_in[10];
    const float* Wo = (const float*)d_in[11];
    const float* bo = (const float*)d_in[12];
    const float* Wf = (const float*)d_in[13];
    const float* bfin = (const float*)d_in[14];
    float* out = (float*)d_out;

    char* ws = (char*)d_ws;
    u16*   WT  = (u16*)  (ws + 0);          // 6291456
    u16*   W2T = (u16*)  (ws + 6291456);    // 2097152
    float* b2  = (float*)(ws + 8388608);    // 4096
    u16*   qbf = (u16*)  (ws + 8392704);    // 8388608
    u16*   kbf = (u16*)  (ws + 16781312);   // 8388608
    u16*   att = (u16*)  (ws + 25169920);   // 8388608
    u16*   vtg = (u16*)  (ws + 33558528);   // 8388608
    float* kb  = (float*)(ws + 41947136);   // 16384  (end ~42 MB)

    hipMemsetAsync(b2, 0, 1024 * sizeof(float), stream);
    transpose_w_kernel<<<dim3(16, 16, 3), 256, 0, stream>>>(Wq, Wk, Wv, WT);
    build_w2t_kernel<<<dim3(16, 16), 256, 0, stream>>>(Wo, bo, Wf, bfin, W2T, b2);
    kbias_kernel<<<dim3(16), 256, 0, stream>>>(kmask, kb);
    gemm_qkv_kernel<<<dim3(768), 512, 0, stream>>>(query, key, value, WT, bq, bk, bv, qbf, kbf, vtg);
    attn_kernel<<<dim3(512), 512, 0, stream>>>(qbf, kbf, vtg, kb, qmask, att);
    gemm_final_kernel<<<dim3(256), 512, 0, stream>>>(att, W2T, b2, out);
}

// Round 21
// 127.030 us; speedup vs baseline: 1.1019x; 1.0177x over previous
//
#include <hip/hip_runtime.h>

typedef unsigned short u16;
typedef unsigned int u32;
typedef __bf16 bf16x8 __attribute__((ext_vector_type(8)));
typedef float f32x4 __attribute__((ext_vector_type(4)));
typedef float f32x16 __attribute__((ext_vector_type(16)));
typedef unsigned short u16x4 __attribute__((ext_vector_type(4)));
typedef unsigned short u16x8 __attribute__((ext_vector_type(8)));
typedef unsigned int u32x2 __attribute__((ext_vector_type(2)));
typedef unsigned int u32x4 __attribute__((ext_vector_type(4)));

#define BB 2
#define SS 2048
#define EE 1024
#define HH 16
#define DD 64

#define QSCALE_F 0.18033688011112042f  /* (1/sqrt(64)) * log2(e) */
#define MSHIFT   12.0f

static __device__ inline u16 f2bf(float f) {
    union { float f; unsigned int u; } v; v.f = f;
    unsigned int u = v.u;
    unsigned int r = (u + 0x7FFFu + ((u >> 16) & 1u)) >> 16;  // RNE
    return (u16)r;
}

static __device__ inline u32 cvt_pk_bf16(float lo, float hi) {
    u32 r;
    asm volatile("v_cvt_pk_bf16_f32 %0, %1, %2" : "=v"(r) : "v"(lo), "v"(hi));
    return r;
}

static __device__ __forceinline__ void gl_lds16(const u16* g, u16* l) {
    __builtin_amdgcn_global_load_lds(
        (const __attribute__((address_space(1))) void*)g,
        (__attribute__((address_space(3))) void*)l, 16, 0, 0);
}

// ---------------- K0a: transpose Wq/Wk/Wv [H,E,D] f32 -> WT [3*1024][1024] bf16 ----------------
__global__ __launch_bounds__(256) void transpose_w_kernel(
    const float* __restrict__ Wq, const float* __restrict__ Wk, const float* __restrict__ Wv,
    u16* __restrict__ WT)
{
    const int z = blockIdx.z;
    const int h = blockIdx.y;
    const int e0 = blockIdx.x * 64;
    const float* W = (z == 0) ? Wq : (z == 1) ? Wk : Wv;
    const float sc = (z == 0) ? QSCALE_F : 1.0f;
    __shared__ float t_lds[64][68];
    const int tid = threadIdx.x;
#pragma unroll
    for (int it = 0; it < 4; ++it) {
        int s = tid + it * 256;
        int i = s >> 4, d4 = (s & 15) * 4;
        const float4 v = *reinterpret_cast<const float4*>(&W[((size_t)h * EE + e0 + i) * DD + d4]);
        t_lds[i][d4 + 0] = v.x; t_lds[i][d4 + 1] = v.y;
        t_lds[i][d4 + 2] = v.z; t_lds[i][d4 + 3] = v.w;
    }
    __syncthreads();
#pragma unroll
    for (int it = 0; it < 4; ++it) {
        int s = tid + it * 256;
        int d = s >> 4, i4 = (s & 15) * 4;
        u16x4 o;
        o[0] = f2bf(t_lds[i4 + 0][d] * sc); o[1] = f2bf(t_lds[i4 + 1][d] * sc);
        o[2] = f2bf(t_lds[i4 + 2][d] * sc); o[3] = f2bf(t_lds[i4 + 3][d] * sc);
        *reinterpret_cast<u16x4*>(&WT[((size_t)z * 1024 + h * 64 + d) * EE + e0 + i4]) = o;
    }
}

// ---------------- K0b: W2T[e][h*D+d] = sum_o Wo[h,d,o]*Wf[h*O+o,e]; b2 ----------------
__global__ __launch_bounds__(256) void build_w2t_kernel(
    const float* __restrict__ Wo, const float* __restrict__ bo,
    const float* __restrict__ Wf, const float* __restrict__ bfin,
    u16* __restrict__ W2T, float* __restrict__ b2)
{
    const int h = blockIdx.y;
    const int e0 = blockIdx.x * 64;
    __shared__ float wo_lds[64][65];  // [d][o]
    __shared__ float wf_lds[64][65];  // [o][i]
    const int tid = threadIdx.x;
#pragma unroll
    for (int it = 0; it < 4; ++it) {
        int s = tid + it * 256;
        int r = s >> 4, c4 = (s & 15) * 4;
        const float4 a = *reinterpret_cast<const float4*>(&Wo[((size_t)h * 64 + r) * 64 + c4]);
        wo_lds[r][c4 + 0] = a.x; wo_lds[r][c4 + 1] = a.y; wo_lds[r][c4 + 2] = a.z; wo_lds[r][c4 + 3] = a.w;
        const float4 b = *reinterpret_cast<const float4*>(&Wf[((size_t)(h * 64 + r)) * EE + e0 + c4]);
        wf_lds[r][c4 + 0] = b.x; wf_lds[r][c4 + 1] = b.y; wf_lds[r][c4 + 2] = b.z; wf_lds[r][c4 + 3] = b.w;
    }
    __syncthreads();
    const int d = tid & 63;
    const int i0 = (tid >> 6) * 16;
#pragma unroll
    for (int ii = 0; ii < 16; ++ii) {
        int i = i0 + ii;
        float acc = 0.f;
#pragma unroll 8
        for (int o = 0; o < 64; ++o) acc += wo_lds[d][o] * wf_lds[o][i];
        W2T[((size_t)(e0 + i)) * 1024 + h * 64 + d] = f2bf(acc);
    }
    if (tid < 64) {
        int i = tid;
        float acc = 0.f;
        for (int o = 0; o < 64; ++o) acc += bo[h * 64 + o] * wf_lds[o][i];
        if (h == 0) acc += bfin[e0 + i];
        atomicAdd(&b2[e0 + i], acc);
    }
}

// ---------------- K1: QKV GEMM — 512 threads, counted-vmcnt depth-2; z==2 writes V^T directly ----------------
__global__ __launch_bounds__(512, 4) void gemm_qkv_kernel(
    const float* __restrict__ query, const float* __restrict__ key, const float* __restrict__ value,
    const u16* __restrict__ WT,
    const float* __restrict__ bq, const float* __restrict__ bk, const float* __restrict__ bv,
    u16* __restrict__ qbf, u16* __restrict__ kbf, u16* __restrict__ vtg)
{
    const int id = blockIdx.x;
    const int xcd = id & 7, idx = id >> 3;       // idx 0..95
    const int p = xcd * 12 + (idx >> 3);         // panel 0..95
    const int z = p >> 5;
    const int m0 = (p & 31) * 128;
    const int n0 = (idx & 7) * 128;

    const float* A   = (z == 0) ? query : (z == 1) ? key : value;
    const float* bia = (z == 0) ? bq    : (z == 1) ? bk  : bv;
    const float bsc  = (z == 0) ? QSCALE_F : 1.0f;
    const u16* BT = WT + (size_t)z * 1024 * 1024;

    __shared__ u16 a_lds[2][128][64];   // 32 KB, swizzled content
    __shared__ u16 b_lds[3][128][64];   // 48 KB

    const int tid = threadIdx.x;
    const int lane = tid & 63;
    const int w = tid >> 6;              // 8 waves
    const int wm = w >> 1, wn = w & 1;   // wave tile: 32 rows x 64 cols
    const int lrow = lane & 15;
    const int lgrp = lane >> 4;

    f32x4 acc[2][4] = {};
    float4 ar0[4], ar1[4];

#define LOADA(ar, k0s)                                                                     \
    do {                                                                                   \
        _Pragma("unroll")                                                                  \
        for (int it = 0; it < 4; ++it) {                                                   \
            int s_ = tid + it * 512;                                                       \
            int row_ = s_ >> 4, c4_ = (s_ & 15) * 4;                                       \
            ar[it] = *reinterpret_cast<const float4*>(&A[(size_t)(m0 + row_) * 1024 + (k0s) + c4_]); \
        }                                                                                  \
    } while (0)

#define STAGEB(bufi, k0s)                                                                  \
    do {                                                                                   \
        _Pragma("unroll")                                                                  \
        for (int it = 0; it < 2; ++it) {                                                   \
            int s_ = tid + it * 512;                                                       \
            int row_ = s_ >> 3;                                                            \
            int sc_ = ((((s_ & 7) * 16) ^ ((row_ & 7) << 4)) >> 1);                        \
            gl_lds16(&BT[(size_t)(n0 + row_) * 1024 + (k0s) + sc_], &b_lds[bufi][0][0] + s_ * 8); \
        }                                                                                  \
    } while (0)

#define WRITEA(bufi, ar)                                                                   \
    do {                                                                                   \
        _Pragma("unroll")                                                                  \
        for (int it = 0; it < 4; ++it) {                                                   \
            int s_ = tid + it * 512;                                                       \
            int row_ = s_ >> 4, c8_ = (s_ & 15) * 8;                                       \
            u32x2 o_;                                                                      \
            o_[0] = cvt_pk_bf16(ar[it].x, ar[it].y);                                       \
            o_[1] = cvt_pk_bf16(ar[it].z, ar[it].w);                                       \
            *reinterpret_cast<u32x2*>(reinterpret_cast<char*>(&a_lds[bufi][0][0]) + row_ * 128 + (c8_ ^ ((row_ & 7) << 4))) = o_; \
        }                                                                                  \
    } while (0)

#define COMPUTE(abuf, bbuf)                                                                \
    do {                                                                                   \
        const char* ab_ = reinterpret_cast<const char*>(&a_lds[abuf][0][0]);               \
        const char* bb_ = reinterpret_cast<const char*>(&b_lds[bbuf][0][0]);               \
        _Pragma("unroll")                                                                  \
        for (int kk = 0; kk < 2; ++kk) {                                                   \
            bf16x8 af[2], bfr[4];                                                          \
            _Pragma("unroll")                                                              \
            for (int i = 0; i < 2; ++i) {                                                  \
                int row = wm * 32 + i * 16 + lrow;                                         \
                af[i] = *reinterpret_cast<const bf16x8*>(ab_ + row * 128 + ((kk * 64 + lgrp * 16) ^ ((row & 7) << 4))); \
            }                                                                              \
            _Pragma("unroll")                                                              \
            for (int j = 0; j < 4; ++j) {                                                  \
                int row = wn * 64 + j * 16 + lrow;                                         \
                bfr[j] = *reinterpret_cast<const bf16x8*>(bb_ + row * 128 + ((kk * 64 + lgrp * 16) ^ ((row & 7) << 4))); \
            }                                                                              \
            _Pragma("unroll")                                                              \
            for (int i = 0; i < 2; ++i)                                                    \
                _Pragma("unroll")                                                          \
                for (int j = 0; j < 4; ++j)                                                \
                    acc[i][j] = __builtin_amdgcn_mfma_f32_16x16x32_bf16(af[i], bfr[j], acc[i][j], 0, 0, 0); \
        }                                                                                  \
    } while (0)

    // prologue: tiles 0 and 1 in flight (12 VMEM/thread); wait first 6 -> tile 0 ready
    LOADA(ar0, 0);
    STAGEB(0, 0);
    LOADA(ar1, 64);
    STAGEB(1, 64);
    asm volatile("s_waitcnt vmcnt(6)" ::: "memory");
    WRITEA(0, ar0);
    asm volatile("s_waitcnt lgkmcnt(0)" ::: "memory");
    __builtin_amdgcn_s_barrier();

#pragma unroll
    for (int t = 0; t < 16; ++t) {
        if (t < 14) {
            if ((t & 1) == 0) LOADA(ar0, (t + 2) * 64);
            else              LOADA(ar1, (t + 2) * 64);
            STAGEB((t + 2) % 3, (t + 2) * 64);
        }

        COMPUTE(t & 1, t % 3);

        if (t < 14)      asm volatile("s_waitcnt vmcnt(6)" ::: "memory");
        else if (t == 14) asm volatile("s_waitcnt vmcnt(0)" ::: "memory");
        if (t < 15) {
            if ((t & 1) == 0) WRITEA(1, ar1);
            else              WRITEA(0, ar0);
            asm volatile("s_waitcnt lgkmcnt(0)" ::: "memory");
            __builtin_amdgcn_s_barrier();
        }
    }
#undef LOADA
#undef STAGEB
#undef WRITEA
#undef COMPUTE

    if (z == 2) {
        // V written pre-transposed: vtg[((b*HH+h)*DD+d)*SS + srow], 4 consecutive srow -> one 8B store.
#pragma unroll
        for (int i = 0; i < 2; ++i) {
#pragma unroll
            for (int j = 0; j < 4; ++j) {
                int n = n0 + wn * 64 + j * 16 + lrow;
                int h = n >> 6, d = n & 63;
                float bb = bia[n];
                int m = m0 + wm * 32 + i * 16 + lgrp * 4;
                int b = m >> 11, srow = m & 2047;
                u16x4 o;
#pragma unroll
                for (int r = 0; r < 4; ++r) o[r] = f2bf(acc[i][j][r] + bb);
                *reinterpret_cast<u16x4*>(&vtg[((size_t)(b * HH + h) * DD + d) * SS + srow]) = o;
            }
        }
    } else {
        u16* outp = (z == 0) ? qbf : kbf;
#pragma unroll
        for (int i = 0; i < 2; ++i) {
#pragma unroll
            for (int j = 0; j < 4; ++j) {
                int n = n0 + wn * 64 + j * 16 + lrow;
                int h = n >> 6, d = n & 63;
                float bb = bia[n] * bsc;
#pragma unroll
                for (int r = 0; r < 4; ++r) {
                    int m = m0 + wm * 32 + i * 16 + lgrp * 4 + r;
                    int b = m >> 11, srow = m & 2047;
                    outp[((size_t)(b * HH + h) * SS + srow) * DD + d] = f2bf(acc[i][j][r] + bb);
                }
            }
        }
    }
}

// ---------------- K2: flash attention — kbias computed inline from kmask in preload ----------------
__global__ __launch_bounds__(512, 4) void attn_kernel(
    const u16* __restrict__ qbf, const u16* __restrict__ kbf, const u16* __restrict__ vtg,
    const float* __restrict__ kmask, const float* __restrict__ qmask,
    u16* __restrict__ att)
{
    const int id = blockIdx.x;
    const int wg = (id & 7) * 64 + (id >> 3);   // XCD-chunked: 4 bh per XCD
    const int bh = wg >> 4, qt = wg & 15;
    const int b = bh >> 4, h = bh & 15;

    const int tid = threadIdx.x;
    const int w = tid >> 6;
    const int lane = tid & 63;
    const int ql = lane & 31, hi = lane >> 5;
    const int qw = w & 3, th = w >> 2;
    const int q0 = qt * 128 + qw * 32;

    __shared__ u16 sm[8][4096];
    __shared__ float kb_lds[2048];

    const size_t bhoff = (size_t)bh * SS * DD;
    const u16* Kb = kbf + bhoff;                    // [2048][64]
    const u16* Vb = vtg + (size_t)bh * DD * SS;     // [64][2048]

    // preload: kbias computed inline from kmask (fused former kbias_kernel)
    {
        float4 kmv = *reinterpret_cast<const float4*>(&kmask[(size_t)b * SS + tid * 4]);
        float4 kbv;
        kbv.x = (kmv.x != 0.f) ? -MSHIFT : -1e38f;
        kbv.y = (kmv.y != 0.f) ? -MSHIFT : -1e38f;
        kbv.z = (kmv.z != 0.f) ? -MSHIFT : -1e38f;
        kbv.w = (kmv.w != 0.f) ? -MSHIFT : -1e38f;
        *reinterpret_cast<float4*>(&kb_lds[tid * 4]) = kbv;
    }

    bf16x8 aq[4];
#pragma unroll
    for (int c = 0; c < 4; ++c)
        aq[c] = *reinterpret_cast<const bf16x8*>(&qbf[bhoff + (size_t)(q0 + ql) * DD + c * 16 + hi * 8]);

    f32x16 acc0 = {}, acc1 = {};
    const f32x16 fz = {};
    float l_run = 0.f;

    const int r_ = tid >> 3;
    const int lch_ = (((tid & 7) * 16) ^ ((r_ & 7) << 4)) >> 1;

#define STAGE(bufi, t64)                                                                   \
    do {                                                                                   \
        gl_lds16(Kb + (size_t)((t64) + r_) * 64 + lch_,          &sm[0 + (bufi)][tid * 8]); \
        gl_lds16(Vb + (size_t)r_ * SS + (t64) + lch_,            &sm[2 + (bufi)][tid * 8]); \
        gl_lds16(Kb + (size_t)(1024 + (t64) + r_) * 64 + lch_,   &sm[4 + (bufi)][tid * 8]); \
        gl_lds16(Vb + (size_t)r_ * SS + 1024 + (t64) + lch_,     &sm[6 + (bufi)][tid * 8]); \
    } while (0)

    STAGE(0, 0);
    asm volatile("s_waitcnt vmcnt(0)" ::: "memory");
    __syncthreads();

    const float* kbl = kb_lds + th * 1024;
    int cur = 0;
    for (int ti = 0; ti < 16; ++ti) {
        const int t0 = ti * 64;
        if (ti < 15) STAGE(cur ^ 1, t0 + 64);

        const char* kbase = reinterpret_cast<const char*>(&sm[th * 4 + cur][0]);
        const char* vbase = reinterpret_cast<const char*>(&sm[th * 4 + 2 + cur][0]);

        float4 km0[4], km1[4];
#pragma unroll
        for (int g = 0; g < 4; ++g) {
            km0[g] = *reinterpret_cast<const float4*>(kbl + t0 + g * 8 + hi * 4);
            km1[g] = *reinterpret_cast<const float4*>(kbl + t0 + 32 + g * 8 + hi * 4);
        }

        const int row0 = ql, row1 = 32 + ql;
        const int swz0 = (row0 & 7) << 4, swz1 = (row1 & 7) << 4;
        f32x16 s0, s1;
        {
            bf16x8 kf0 = *reinterpret_cast<const bf16x8*>(kbase + row0 * 128 + ((0 * 32 + hi * 16) ^ swz0));
            bf16x8 kf1 = *reinterpret_cast<const bf16x8*>(kbase + row1 * 128 + ((0 * 32 + hi * 16) ^ swz1));
            s0 = __builtin_amdgcn_mfma_f32_32x32x16_bf16(kf0, aq[0], fz, 0, 0, 0);
            s1 = __builtin_amdgcn_mfma_f32_32x32x16_bf16(kf1, aq[0], fz, 0, 0, 0);
        }
#pragma unroll
        for (int c = 1; c < 4; ++c) {
            bf16x8 kf0 = *reinterpret_cast<const bf16x8*>(kbase + row0 * 128 + ((c * 32 + hi * 16) ^ swz0));
            bf16x8 kf1 = *reinterpret_cast<const bf16x8*>(kbase + row1 * 128 + ((c * 32 + hi * 16) ^ swz1));
            s0 = __builtin_amdgcn_mfma_f32_32x32x16_bf16(kf0, aq[c], s0, 0, 0, 0);
            s1 = __builtin_amdgcn_mfma_f32_32x32x16_bf16(kf1, aq[c], s1, 0, 0, 0);
        }

        float p0[16], p1[16];
        float ps0 = 0.f, ps1 = 0.f, ps2 = 0.f, ps3 = 0.f;
#pragma unroll
        for (int r = 0; r < 16; ++r) {
            float kv0 = (r & 1) ? ((r & 2) ? km0[r >> 2].w : km0[r >> 2].y)
                                : ((r & 2) ? km0[r >> 2].z : km0[r >> 2].x);
            float kv1 = (r & 1) ? ((r & 2) ? km1[r >> 2].w : km1[r >> 2].y)
                                : ((r & 2) ? km1[r >> 2].z : km1[r >> 2].x);
            float e0 = __builtin_amdgcn_exp2f(s0[r] + kv0);
            float e1 = __builtin_amdgcn_exp2f(s1[r] + kv1);
            p0[r] = e0; p1[r] = e1;
            if (r & 1) { ps1 += e0; ps3 += e1; } else { ps0 += e0; ps2 += e1; }
        }
        l_run += (ps0 + ps1) + (ps2 + ps3);

        bf16x8 pw[4];
#pragma unroll
        for (int hf = 0; hf < 2; ++hf) {
            {
                u32 x1 = cvt_pk_bf16(p0[hf * 8 + 0], p0[hf * 8 + 1]);
                u32 x2 = cvt_pk_bf16(p0[hf * 8 + 2], p0[hf * 8 + 3]);
                u32 y1 = cvt_pk_bf16(p0[hf * 8 + 4], p0[hf * 8 + 5]);
                u32 y2 = cvt_pk_bf16(p0[hf * 8 + 6], p0[hf * 8 + 7]);
                u32x2 sA = __builtin_amdgcn_permlane32_swap(x1, y1, false, false);
                u32x2 sB = __builtin_amdgcn_permlane32_swap(x2, y2, false, false);
                u32x4 fr; fr[0] = sA[0]; fr[1] = sB[0]; fr[2] = sA[1]; fr[3] = sB[1];
                pw[hf] = __builtin_bit_cast(bf16x8, fr);
            }
            {
                u32 x1 = cvt_pk_bf16(p1[hf * 8 + 0], p1[hf * 8 + 1]);
                u32 x2 = cvt_pk_bf16(p1[hf * 8 + 2], p1[hf * 8 + 3]);
                u32 y1 = cvt_pk_bf16(p1[hf * 8 + 4], p1[hf * 8 + 5]);
                u32 y2 = cvt_pk_bf16(p1[hf * 8 + 6], p1[hf * 8 + 7]);
                u32x2 sA = __builtin_amdgcn_permlane32_swap(x1, y1, false, false);
                u32x2 sB = __builtin_amdgcn_permlane32_swap(x2, y2, false, false);
                u32x4 fr; fr[0] = sA[0]; fr[1] = sB[0]; fr[2] = sA[1]; fr[3] = sB[1];
                pw[2 + hf] = __builtin_bit_cast(bf16x8, fr);
            }
        }

#pragma unroll
        for (int cc = 0; cc < 4; ++cc) {
            bf16x8 vf0 = *reinterpret_cast<const bf16x8*>(vbase + row0 * 128 + ((cc * 32 + hi * 16) ^ swz0));
            bf16x8 vf1 = *reinterpret_cast<const bf16x8*>(vbase + row1 * 128 + ((cc * 32 + hi * 16) ^ swz1));
            acc0 = __builtin_amdgcn_mfma_f32_32x32x16_bf16(vf0, pw[cc], acc0, 0, 0, 0);
            acc1 = __builtin_amdgcn_mfma_f32_32x32x16_bf16(vf1, pw[cc], acc1, 0, 0, 0);
        }

        asm volatile("s_waitcnt vmcnt(0)" ::: "memory");
        __syncthreads();
        cur ^= 1;
    }
#undef STAGE

    float* cb = reinterpret_cast<float*>(&sm[0][0]);
    const int ci = (qw * 64 + lane) * 34;
    if (th == 1) {
#pragma unroll
        for (int r = 0; r < 16; ++r) { cb[ci + r] = acc0[r]; cb[ci + 16 + r] = acc1[r]; }
        cb[ci + 32] = l_run;
    }
    __syncthreads();
    if (th == 0) {
#pragma unroll
        for (int r = 0; r < 16; ++r) { acc0[r] += cb[ci + r]; acc1[r] += cb[ci + 16 + r]; }
        l_run += cb[ci + 32];

        float l1 = l_run + __shfl_xor(l_run, 32);
        float qm = qmask[(size_t)b * SS + q0 + ql];
        float inv = (l1 > 0.f && qm != 0.f) ? 1.f / l1 : 0.f;
        u16* orow = att + ((size_t)b * SS + q0 + ql) * 1024 + h * 64;
#pragma unroll
        for (int c = 0; c < 4; ++c)
#pragma unroll
            for (int pp = 0; pp < 2; ++pp) {
                int d0 = 8 * c + 4 * hi + 2 * pp;
                u32 w0 = cvt_pk_bf16(acc0[4 * c + 2 * pp] * inv, acc0[4 * c + 2 * pp + 1] * inv);
                u32 w1 = cvt_pk_bf16(acc1[4 * c + 2 * pp] * inv, acc1[4 * c + 2 * pp + 1] * inv);
                *reinterpret_cast<u32*>(orow + d0) = w0;
                *reinterpret_cast<u32*>(orow + 32 + d0) = w1;
            }
    }
}

// ---------------- K3: final GEMM — 512 threads (8 waves), counted-vmcnt depth-2 pipeline ----------------
__global__ __launch_bounds__(512, 2) void gemm_final_kernel(
    const u16* __restrict__ A, const u16* __restrict__ BT,
    const float* __restrict__ b2, float* __restrict__ out)
{
    const int id = blockIdx.x;
    const int xcd = id & 7, idx = id >> 3;       // idx 0..31
    const int p = xcd * 4 + (idx >> 3);          // m-panel 0..31
    const int m0 = p * 128;
    const int n0 = (idx & 7) * 128;

    __shared__ u16 a_lds[3][128][64];
    __shared__ u16 b_lds[3][128][64];

    const int tid = threadIdx.x;
    const int lane = tid & 63;
    const int w = tid >> 6;              // 8 waves
    const int wm = w >> 1, wn = w & 1;   // wave tile: 32 rows x 64 cols
    const int lrow = lane & 15;
    const int lgrp = lane >> 4;

    f32x4 acc[2][4] = {};

#define STAGEF(bufi, k0s)                                                                  \
    do {                                                                                   \
        _Pragma("unroll")                                                                  \
        for (int it = 0; it < 2; ++it) {                                                   \
            int s_ = tid + it * 512;                                                       \
            int row_ = s_ >> 3;                                                            \
            int sc_ = ((((s_ & 7) * 16) ^ ((row_ & 7) << 4)) >> 1);                        \
            gl_lds16(&A[(size_t)(m0 + row_) * 1024 + (k0s) + sc_], &a_lds[bufi][0][0] + s_ * 8);  \
            gl_lds16(&BT[(size_t)(n0 + row_) * 1024 + (k0s) + sc_], &b_lds[bufi][0][0] + s_ * 8); \
        }                                                                                  \
    } while (0)

#define COMPUTEF(bufi)                                                                     \
    do {                                                                                   \
        const char* ab_ = reinterpret_cast<const char*>(&a_lds[bufi][0][0]);               \
        const char* bb_ = reinterpret_cast<const char*>(&b_lds[bufi][0][0]);               \
        _Pragma("unroll")                                                                  \
        for (int kk = 0; kk < 2; ++kk) {                                                   \
            bf16x8 af[2], bfr[4];                                                          \
            _Pragma("unroll")                                                              \
            for (int i = 0; i < 2; ++i) {                                                  \
                int row = wm * 32 + i * 16 + lrow;                                         \
                af[i] = *reinterpret_cast<const bf16x8*>(ab_ + row * 128 + ((kk * 64 + lgrp * 16) ^ ((row & 7) << 4))); \
            }                                                                              \
            _Pragma("unroll")                                                              \
            for (int j = 0; j < 4; ++j) {                                                  \
                int row = wn * 64 + j * 16 + lrow;                                         \
                bfr[j] = *reinterpret_cast<const bf16x8*>(bb_ + row * 128 + ((kk * 64 + lgrp * 16) ^ ((row & 7) << 4))); \
            }                                                                              \
            _Pragma("unroll")                                                              \
            for (int i = 0; i < 2; ++i)                                                    \
                _Pragma("unroll")                                                          \
                for (int j = 0; j < 4; ++j)                                                \
                    acc[i][j] = __builtin_amdgcn_mfma_f32_16x16x32_bf16(af[i], bfr[j], acc[i][j], 0, 0, 0); \
        }                                                                                  \
    } while (0)

    STAGEF(0, 0);
    STAGEF(1, 64);
    asm volatile("s_waitcnt vmcnt(4)" ::: "memory");
    __builtin_amdgcn_s_barrier();

#pragma unroll
    for (int t = 0; t < 16; ++t) {
        if (t < 14) STAGEF((t + 2) % 3, (t + 2) * 64);

        COMPUTEF(t % 3);

        if (t < 14)       asm volatile("s_waitcnt vmcnt(4)" ::: "memory");
        else if (t == 14) asm volatile("s_waitcnt vmcnt(0)" ::: "memory");
        if (t < 15) __builtin_amdgcn_s_barrier();
    }
#undef STAGEF
#undef COMPUTEF

#pragma unroll
    for (int i = 0; i < 2; ++i) {
#pragma unroll
        for (int j = 0; j < 4; ++j) {
            int n = n0 + wn * 64 + j * 16 + lrow;
            float bb = b2[n];
#pragma unroll
            for (int r = 0; r < 4; ++r) {
                int m = m0 + wm * 32 + i * 16 + lgrp * 4 + r;
                out[(size_t)m * 1024 + n] = acc[i][j][r] + bb;
            }
        }
    }
}

extern "C" void kernel_launch(void* const* d_in, const int* in_sizes, int n_in,
                              void* d_out, int out_size, void* d_ws, size_t ws_size,
                              hipStream_t stream) {
    const float* query = (const float*)d_in[0];
    const float* key   = (const float*)d_in[1];
    const float* value = (const float*)d_in[2];
    const float* qmask = (const float*)d_in[3];
    const float* kmask = (const float*)d_in[4];
    const float* Wq = (const float*)d_in[5];
    const float* bq = (const float*)d_in[6];
    const float* Wk = (const float*)d_in[7];
    const float* bk = (const float*)d_in[8];
    const float* Wv = (const float*)d_in[9];
    const float* bv = (const float*)d_in[10];
    const float* Wo = (const float*)d_in[11];
    const float* bo = (const float*)d_in[12];
    const float* Wf = (const float*)d_in[13];
    const float* bfin = (const float*)d_in[14];
    float* out = (float*)d_out;

    char* ws = (char*)d_ws;
    u16*   WT  = (u16*)  (ws + 0);          // 6291456
    u16*   W2T = (u16*)  (ws + 6291456);    // 2097152
    float* b2  = (float*)(ws + 8388608);    // 4096
    u16*   qbf = (u16*)  (ws + 8392704);    // 8388608
    u16*   kbf = (u16*)  (ws + 16781312);   // 8388608
    u16*   att = (u16*)  (ws + 25169920);   // 8388608
    u16*   vtg = (u16*)  (ws + 33558528);   // 8388608  (end ~42 MB)

    hipMemsetAsync(b2, 0, 1024 * sizeof(float), stream);
    transpose_w_kernel<<<dim3(16, 16, 3), 256, 0, stream>>>(Wq, Wk, Wv, WT);
    build_w2t_kernel<<<dim3(16, 16), 256, 0, stream>>>(Wo, bo, Wf, bfin, W2T, b2);
    gemm_qkv_kernel<<<dim3(768), 512, 0, stream>>>(query, key, value, WT, bq, bk, bv, qbf, kbf, vtg);
    attn_kernel<<<dim3(512), 512, 0, stream>>>(qbf, kbf, vtg, kmask, qmask, att);
    gemm_final_kernel<<<dim3(256), 512, 0, stream>>>(att, W2T, b2, out);
}

// Round 22
// 123.326 us; speedup vs baseline: 1.1350x; 1.0300x over previous
//
#include <hip/hip_runtime.h>

typedef unsigned short u16;
typedef unsigned int u32;
typedef __bf16 bf16x8 __attribute__((ext_vector_type(8)));
typedef float f32x4 __attribute__((ext_vector_type(4)));
typedef float f32x16 __attribute__((ext_vector_type(16)));
typedef unsigned short u16x4 __attribute__((ext_vector_type(4)));
typedef unsigned short u16x8 __attribute__((ext_vector_type(8)));
typedef unsigned int u32x2 __attribute__((ext_vector_type(2)));
typedef unsigned int u32x4 __attribute__((ext_vector_type(4)));

#define BB 2
#define SS 2048
#define EE 1024
#define HH 16
#define DD 64

#define QSCALE_F 0.18033688011112042f  /* (1/sqrt(64)) * log2(e) */
#define MSHIFT   12.0f

static __device__ inline u16 f2bf(float f) {
    union { float f; unsigned int u; } v; v.f = f;
    unsigned int u = v.u;
    unsigned int r = (u + 0x7FFFu + ((u >> 16) & 1u)) >> 16;  // RNE
    return (u16)r;
}

static __device__ inline u32 cvt_pk_bf16(float lo, float hi) {
    u32 r;
    asm volatile("v_cvt_pk_bf16_f32 %0, %1, %2" : "=v"(r) : "v"(lo), "v"(hi));
    return r;
}

static __device__ __forceinline__ void gl_lds16(const u16* g, u16* l) {
    __builtin_amdgcn_global_load_lds(
        (const __attribute__((address_space(1))) void*)g,
        (__attribute__((address_space(3))) void*)l, 16, 0, 0);
}

// ---------------- K0: fused prep — blocks [0,768): transpose W; blocks [768,1024): build W2T/b2 ----------------
__global__ __launch_bounds__(256) void prep_kernel(
    const float* __restrict__ Wq, const float* __restrict__ Wk, const float* __restrict__ Wv,
    const float* __restrict__ Wo, const float* __restrict__ bo,
    const float* __restrict__ Wf, const float* __restrict__ bfin,
    u16* __restrict__ WT, u16* __restrict__ W2T, float* __restrict__ b2)
{
    const int id = blockIdx.x;
    const int tid = threadIdx.x;

    __shared__ float lds_a[64][68];
    __shared__ float lds_b[64][68];   // union covers both roles (transpose uses lds_a only)

    if (id < 768) {
        // ---- transpose_w body ----
        const int z = id >> 8;
        const int h = (id >> 4) & 15;
        const int e0 = (id & 15) * 64;
        const float* W = (z == 0) ? Wq : (z == 1) ? Wk : Wv;
        const float sc = (z == 0) ? QSCALE_F : 1.0f;
#pragma unroll
        for (int it = 0; it < 4; ++it) {
            int s = tid + it * 256;
            int i = s >> 4, d4 = (s & 15) * 4;
            const float4 v = *reinterpret_cast<const float4*>(&W[((size_t)h * EE + e0 + i) * DD + d4]);
            lds_a[i][d4 + 0] = v.x; lds_a[i][d4 + 1] = v.y;
            lds_a[i][d4 + 2] = v.z; lds_a[i][d4 + 3] = v.w;
        }
        __syncthreads();
#pragma unroll
        for (int it = 0; it < 4; ++it) {
            int s = tid + it * 256;
            int d = s >> 4, i4 = (s & 15) * 4;
            u16x4 o;
            o[0] = f2bf(lds_a[i4 + 0][d] * sc); o[1] = f2bf(lds_a[i4 + 1][d] * sc);
            o[2] = f2bf(lds_a[i4 + 2][d] * sc); o[3] = f2bf(lds_a[i4 + 3][d] * sc);
            *reinterpret_cast<u16x4*>(&WT[((size_t)z * 1024 + h * 64 + d) * EE + e0 + i4]) = o;
        }
    } else {
        // ---- build_w2t body ----
        const int idx2 = id - 768;
        const int h = idx2 >> 4;
        const int e0 = (idx2 & 15) * 64;
#pragma unroll
        for (int it = 0; it < 4; ++it) {
            int s = tid + it * 256;
            int r = s >> 4, c4 = (s & 15) * 4;
            const float4 a = *reinterpret_cast<const float4*>(&Wo[((size_t)h * 64 + r) * 64 + c4]);
            lds_a[r][c4 + 0] = a.x; lds_a[r][c4 + 1] = a.y; lds_a[r][c4 + 2] = a.z; lds_a[r][c4 + 3] = a.w;
            const float4 b = *reinterpret_cast<const float4*>(&Wf[((size_t)(h * 64 + r)) * EE + e0 + c4]);
            lds_b[r][c4 + 0] = b.x; lds_b[r][c4 + 1] = b.y; lds_b[r][c4 + 2] = b.z; lds_b[r][c4 + 3] = b.w;
        }
        __syncthreads();
        const int d = tid & 63;
        const int i0 = (tid >> 6) * 16;
#pragma unroll
        for (int ii = 0; ii < 16; ++ii) {
            int i = i0 + ii;
            float acc = 0.f;
#pragma unroll 8
            for (int o = 0; o < 64; ++o) acc += lds_a[d][o] * lds_b[o][i];
            W2T[((size_t)(e0 + i)) * 1024 + h * 64 + d] = f2bf(acc);
        }
        if (tid < 64) {
            int i = tid;
            float acc = 0.f;
            for (int o = 0; o < 64; ++o) acc += bo[h * 64 + o] * lds_b[o][i];
            if (h == 0) acc += bfin[e0 + i];
            atomicAdd(&b2[e0 + i], acc);
        }
    }
}

// ---------------- K1: QKV GEMM — 512 threads, counted-vmcnt depth-2; z==2 writes V^T directly ----------------
__global__ __launch_bounds__(512, 4) void gemm_qkv_kernel(
    const float* __restrict__ query, const float* __restrict__ key, const float* __restrict__ value,
    const u16* __restrict__ WT,
    const float* __restrict__ bq, const float* __restrict__ bk, const float* __restrict__ bv,
    u16* __restrict__ qbf, u16* __restrict__ kbf, u16* __restrict__ vtg)
{
    const int id = blockIdx.x;
    const int xcd = id & 7, idx = id >> 3;       // idx 0..95
    const int p = xcd * 12 + (idx >> 3);         // panel 0..95
    const int z = p >> 5;
    const int m0 = (p & 31) * 128;
    const int n0 = (idx & 7) * 128;

    const float* A   = (z == 0) ? query : (z == 1) ? key : value;
    const float* bia = (z == 0) ? bq    : (z == 1) ? bk  : bv;
    const float bsc  = (z == 0) ? QSCALE_F : 1.0f;
    const u16* BT = WT + (size_t)z * 1024 * 1024;

    __shared__ u16 a_lds[2][128][64];   // 32 KB, swizzled content
    __shared__ u16 b_lds[3][128][64];   // 48 KB

    const int tid = threadIdx.x;
    const int lane = tid & 63;
    const int w = tid >> 6;              // 8 waves
    const int wm = w >> 1, wn = w & 1;   // wave tile: 32 rows x 64 cols
    const int lrow = lane & 15;
    const int lgrp = lane >> 4;

    f32x4 acc[2][4] = {};
    float4 ar0[4], ar1[4];

#define LOADA(ar, k0s)                                                                     \
    do {                                                                                   \
        _Pragma("unroll")                                                                  \
        for (int it = 0; it < 4; ++it) {                                                   \
            int s_ = tid + it * 512;                                                       \
            int row_ = s_ >> 4, c4_ = (s_ & 15) * 4;                                       \
            ar[it] = *reinterpret_cast<const float4*>(&A[(size_t)(m0 + row_) * 1024 + (k0s) + c4_]); \
        }                                                                                  \
    } while (0)

#define STAGEB(bufi, k0s)                                                                  \
    do {                                                                                   \
        _Pragma("unroll")                                                                  \
        for (int it = 0; it < 2; ++it) {                                                   \
            int s_ = tid + it * 512;                                                       \
            int row_ = s_ >> 3;                                                            \
            int sc_ = ((((s_ & 7) * 16) ^ ((row_ & 7) << 4)) >> 1);                        \
            gl_lds16(&BT[(size_t)(n0 + row_) * 1024 + (k0s) + sc_], &b_lds[bufi][0][0] + s_ * 8); \
        }                                                                                  \
    } while (0)

#define WRITEA(bufi, ar)                                                                   \
    do {                                                                                   \
        _Pragma("unroll")                                                                  \
        for (int it = 0; it < 4; ++it) {                                                   \
            int s_ = tid + it * 512;                                                       \
            int row_ = s_ >> 4, c8_ = (s_ & 15) * 8;                                       \
            u32x2 o_;                                                                      \
            o_[0] = cvt_pk_bf16(ar[it].x, ar[it].y);                                       \
            o_[1] = cvt_pk_bf16(ar[it].z, ar[it].w);                                       \
            *reinterpret_cast<u32x2*>(reinterpret_cast<char*>(&a_lds[bufi][0][0]) + row_ * 128 + (c8_ ^ ((row_ & 7) << 4))) = o_; \
        }                                                                                  \
    } while (0)

#define COMPUTE(abuf, bbuf)                                                                \
    do {                                                                                   \
        const char* ab_ = reinterpret_cast<const char*>(&a_lds[abuf][0][0]);               \
        const char* bb_ = reinterpret_cast<const char*>(&b_lds[bbuf][0][0]);               \
        _Pragma("unroll")                                                                  \
        for (int kk = 0; kk < 2; ++kk) {                                                   \
            bf16x8 af[2], bfr[4];                                                          \
            _Pragma("unroll")                                                              \
            for (int i = 0; i < 2; ++i) {                                                  \
                int row = wm * 32 + i * 16 + lrow;                                         \
                af[i] = *reinterpret_cast<const bf16x8*>(ab_ + row * 128 + ((kk * 64 + lgrp * 16) ^ ((row & 7) << 4))); \
            }                                                                              \
            _Pragma("unroll")                                                              \
            for (int j = 0; j < 4; ++j) {                                                  \
                int row = wn * 64 + j * 16 + lrow;                                         \
                bfr[j] = *reinterpret_cast<const bf16x8*>(bb_ + row * 128 + ((kk * 64 + lgrp * 16) ^ ((row & 7) << 4))); \
            }                                                                              \
            _Pragma("unroll")                                                              \
            for (int i = 0; i < 2; ++i)                                                    \
                _Pragma("unroll")                                                          \
                for (int j = 0; j < 4; ++j)                                                \
                    acc[i][j] = __builtin_amdgcn_mfma_f32_16x16x32_bf16(af[i], bfr[j], acc[i][j], 0, 0, 0); \
        }                                                                                  \
    } while (0)

    // prologue: tiles 0 and 1 in flight (12 VMEM/thread); wait first 6 -> tile 0 ready
    LOADA(ar0, 0);
    STAGEB(0, 0);
    LOADA(ar1, 64);
    STAGEB(1, 64);
    asm volatile("s_waitcnt vmcnt(6)" ::: "memory");
    WRITEA(0, ar0);
    asm volatile("s_waitcnt lgkmcnt(0)" ::: "memory");
    __builtin_amdgcn_s_barrier();

#pragma unroll
    for (int t = 0; t < 16; ++t) {
        if (t < 14) {
            if ((t & 1) == 0) LOADA(ar0, (t + 2) * 64);
            else              LOADA(ar1, (t + 2) * 64);
            STAGEB((t + 2) % 3, (t + 2) * 64);
        }

        COMPUTE(t & 1, t % 3);

        if (t < 14)      asm volatile("s_waitcnt vmcnt(6)" ::: "memory");
        else if (t == 14) asm volatile("s_waitcnt vmcnt(0)" ::: "memory");
        if (t < 15) {
            if ((t & 1) == 0) WRITEA(1, ar1);
            else              WRITEA(0, ar0);
            asm volatile("s_waitcnt lgkmcnt(0)" ::: "memory");
            __builtin_amdgcn_s_barrier();
        }
    }
#undef LOADA
#undef STAGEB
#undef WRITEA
#undef COMPUTE

    if (z == 2) {
        // V written pre-transposed: vtg[((b*HH+h)*DD+d)*SS + srow], 4 consecutive srow -> one 8B store.
#pragma unroll
        for (int i = 0; i < 2; ++i) {
#pragma unroll
            for (int j = 0; j < 4; ++j) {
                int n = n0 + wn * 64 + j * 16 + lrow;
                int h = n >> 6, d = n & 63;
                float bb = bia[n];
                int m = m0 + wm * 32 + i * 16 + lgrp * 4;
                int b = m >> 11, srow = m & 2047;
                u16x4 o;
#pragma unroll
                for (int r = 0; r < 4; ++r) o[r] = f2bf(acc[i][j][r] + bb);
                *reinterpret_cast<u16x4*>(&vtg[((size_t)(b * HH + h) * DD + d) * SS + srow]) = o;
            }
        }
    } else {
        u16* outp = (z == 0) ? qbf : kbf;
#pragma unroll
        for (int i = 0; i < 2; ++i) {
#pragma unroll
            for (int j = 0; j < 4; ++j) {
                int n = n0 + wn * 64 + j * 16 + lrow;
                int h = n >> 6, d = n & 63;
                float bb = bia[n] * bsc;
#pragma unroll
                for (int r = 0; r < 4; ++r) {
                    int m = m0 + wm * 32 + i * 16 + lgrp * 4 + r;
                    int b = m >> 11, srow = m & 2047;
                    outp[((size_t)(b * HH + h) * SS + srow) * DD + d] = f2bf(acc[i][j][r] + bb);
                }
            }
        }
    }
}

// ---------------- K2: flash attention — kbias computed inline from kmask in preload ----------------
__global__ __launch_bounds__(512, 4) void attn_kernel(
    const u16* __restrict__ qbf, const u16* __restrict__ kbf, const u16* __restrict__ vtg,
    const float* __restrict__ kmask, const float* __restrict__ qmask,
    u16* __restrict__ att)
{
    const int id = blockIdx.x;
    const int wg = (id & 7) * 64 + (id >> 3);   // XCD-chunked: 4 bh per XCD
    const int bh = wg >> 4, qt = wg & 15;
    const int b = bh >> 4, h = bh & 15;

    const int tid = threadIdx.x;
    const int w = tid >> 6;
    const int lane = tid & 63;
    const int ql = lane & 31, hi = lane >> 5;
    const int qw = w & 3, th = w >> 2;
    const int q0 = qt * 128 + qw * 32;

    __shared__ u16 sm[8][4096];
    __shared__ float kb_lds[2048];

    const size_t bhoff = (size_t)bh * SS * DD;
    const u16* Kb = kbf + bhoff;                    // [2048][64]
    const u16* Vb = vtg + (size_t)bh * DD * SS;     // [64][2048]

    // preload: kbias computed inline from kmask (fused former kbias_kernel)
    {
        float4 kmv = *reinterpret_cast<const float4*>(&kmask[(size_t)b * SS + tid * 4]);
        float4 kbv;
        kbv.x = (kmv.x != 0.f) ? -MSHIFT : -1e38f;
        kbv.y = (kmv.y != 0.f) ? -MSHIFT : -1e38f;
        kbv.z = (kmv.z != 0.f) ? -MSHIFT : -1e38f;
        kbv.w = (kmv.w != 0.f) ? -MSHIFT : -1e38f;
        *reinterpret_cast<float4*>(&kb_lds[tid * 4]) = kbv;
    }

    bf16x8 aq[4];
#pragma unroll
    for (int c = 0; c < 4; ++c)
        aq[c] = *reinterpret_cast<const bf16x8*>(&qbf[bhoff + (size_t)(q0 + ql) * DD + c * 16 + hi * 8]);

    f32x16 acc0 = {}, acc1 = {};
    const f32x16 fz = {};
    float l_run = 0.f;

    const int r_ = tid >> 3;
    const int lch_ = (((tid & 7) * 16) ^ ((r_ & 7) << 4)) >> 1;

#define STAGE(bufi, t64)                                                                   \
    do {                                                                                   \
        gl_lds16(Kb + (size_t)((t64) + r_) * 64 + lch_,          &sm[0 + (bufi)][tid * 8]); \
        gl_lds16(Vb + (size_t)r_ * SS + (t64) + lch_,            &sm[2 + (bufi)][tid * 8]); \
        gl_lds16(Kb + (size_t)(1024 + (t64) + r_) * 64 + lch_,   &sm[4 + (bufi)][tid * 8]); \
        gl_lds16(Vb + (size_t)r_ * SS + 1024 + (t64) + lch_,     &sm[6 + (bufi)][tid * 8]); \
    } while (0)

    STAGE(0, 0);
    asm volatile("s_waitcnt vmcnt(0)" ::: "memory");
    __syncthreads();

    const float* kbl = kb_lds + th * 1024;
    int cur = 0;
    for (int ti = 0; ti < 16; ++ti) {
        const int t0 = ti * 64;
        if (ti < 15) STAGE(cur ^ 1, t0 + 64);

        const char* kbase = reinterpret_cast<const char*>(&sm[th * 4 + cur][0]);
        const char* vbase = reinterpret_cast<const char*>(&sm[th * 4 + 2 + cur][0]);

        float4 km0[4], km1[4];
#pragma unroll
        for (int g = 0; g < 4; ++g) {
            km0[g] = *reinterpret_cast<const float4*>(kbl + t0 + g * 8 + hi * 4);
            km1[g] = *reinterpret_cast<const float4*>(kbl + t0 + 32 + g * 8 + hi * 4);
        }

        const int row0 = ql, row1 = 32 + ql;
        const int swz0 = (row0 & 7) << 4, swz1 = (row1 & 7) << 4;
        f32x16 s0, s1;
        {
            bf16x8 kf0 = *reinterpret_cast<const bf16x8*>(kbase + row0 * 128 + ((0 * 32 + hi * 16) ^ swz0));
            bf16x8 kf1 = *reinterpret_cast<const bf16x8*>(kbase + row1 * 128 + ((0 * 32 + hi * 16) ^ swz1));
            s0 = __builtin_amdgcn_mfma_f32_32x32x16_bf16(kf0, aq[0], fz, 0, 0, 0);
            s1 = __builtin_amdgcn_mfma_f32_32x32x16_bf16(kf1, aq[0], fz, 0, 0, 0);
        }
#pragma unroll
        for (int c = 1; c < 4; ++c) {
            bf16x8 kf0 = *reinterpret_cast<const bf16x8*>(kbase + row0 * 128 + ((c * 32 + hi * 16) ^ swz0));
            bf16x8 kf1 = *reinterpret_cast<const bf16x8*>(kbase + row1 * 128 + ((c * 32 + hi * 16) ^ swz1));
            s0 = __builtin_amdgcn_mfma_f32_32x32x16_bf16(kf0, aq[c], s0, 0, 0, 0);
            s1 = __builtin_amdgcn_mfma_f32_32x32x16_bf16(kf1, aq[c], s1, 0, 0, 0);
        }

        float p0[16], p1[16];
        float ps0 = 0.f, ps1 = 0.f, ps2 = 0.f, ps3 = 0.f;
#pragma unroll
        for (int r = 0; r < 16; ++r) {
            float kv0 = (r & 1) ? ((r & 2) ? km0[r >> 2].w : km0[r >> 2].y)
                                : ((r & 2) ? km0[r >> 2].z : km0[r >> 2].x);
            float kv1 = (r & 1) ? ((r & 2) ? km1[r >> 2].w : km1[r >> 2].y)
                                : ((r & 2) ? km1[r >> 2].z : km1[r >> 2].x);
            float e0 = __builtin_amdgcn_exp2f(s0[r] + kv0);
            float e1 = __builtin_amdgcn_exp2f(s1[r] + kv1);
            p0[r] = e0; p1[r] = e1;
            if (r & 1) { ps1 += e0; ps3 += e1; } else { ps0 += e0; ps2 += e1; }
        }
        l_run += (ps0 + ps1) + (ps2 + ps3);

        bf16x8 pw[4];
#pragma unroll
        for (int hf = 0; hf < 2; ++hf) {
            {
                u32 x1 = cvt_pk_bf16(p0[hf * 8 + 0], p0[hf * 8 + 1]);
                u32 x2 = cvt_pk_bf16(p0[hf * 8 + 2], p0[hf * 8 + 3]);
                u32 y1 = cvt_pk_bf16(p0[hf * 8 + 4], p0[hf * 8 + 5]);
                u32 y2 = cvt_pk_bf16(p0[hf * 8 + 6], p0[hf * 8 + 7]);
                u32x2 sA = __builtin_amdgcn_permlane32_swap(x1, y1, false, false);
                u32x2 sB = __builtin_amdgcn_permlane32_swap(x2, y2, false, false);
                u32x4 fr; fr[0] = sA[0]; fr[1] = sB[0]; fr[2] = sA[1]; fr[3] = sB[1];
                pw[hf] = __builtin_bit_cast(bf16x8, fr);
            }
            {
                u32 x1 = cvt_pk_bf16(p1[hf * 8 + 0], p1[hf * 8 + 1]);
                u32 x2 = cvt_pk_bf16(p1[hf * 8 + 2], p1[hf * 8 + 3]);
                u32 y1 = cvt_pk_bf16(p1[hf * 8 + 4], p1[hf * 8 + 5]);
                u32 y2 = cvt_pk_bf16(p1[hf * 8 + 6], p1[hf * 8 + 7]);
                u32x2 sA = __builtin_amdgcn_permlane32_swap(x1, y1, false, false);
                u32x2 sB = __builtin_amdgcn_permlane32_swap(x2, y2, false, false);
                u32x4 fr; fr[0] = sA[0]; fr[1] = sB[0]; fr[2] = sA[1]; fr[3] = sB[1];
                pw[2 + hf] = __builtin_bit_cast(bf16x8, fr);
            }
        }

#pragma unroll
        for (int cc = 0; cc < 4; ++cc) {
            bf16x8 vf0 = *reinterpret_cast<const bf16x8*>(vbase + row0 * 128 + ((cc * 32 + hi * 16) ^ swz0));
            bf16x8 vf1 = *reinterpret_cast<const bf16x8*>(vbase + row1 * 128 + ((cc * 32 + hi * 16) ^ swz1));
            acc0 = __builtin_amdgcn_mfma_f32_32x32x16_bf16(vf0, pw[cc], acc0, 0, 0, 0);
            acc1 = __builtin_amdgcn_mfma_f32_32x32x16_bf16(vf1, pw[cc], acc1, 0, 0, 0);
        }

        asm volatile("s_waitcnt vmcnt(0)" ::: "memory");
        __syncthreads();
        cur ^= 1;
    }
#undef STAGE

    float* cb = reinterpret_cast<float*>(&sm[0][0]);
    const int ci = (qw * 64 + lane) * 34;
    if (th == 1) {
#pragma unroll
        for (int r = 0; r < 16; ++r) { cb[ci + r] = acc0[r]; cb[ci + 16 + r] = acc1[r]; }
        cb[ci + 32] = l_run;
    }
    __syncthreads();
    if (th == 0) {
#pragma unroll
        for (int r = 0; r < 16; ++r) { acc0[r] += cb[ci + r]; acc1[r] += cb[ci + 16 + r]; }
        l_run += cb[ci + 32];

        float l1 = l_run + __shfl_xor(l_run, 32);
        float qm = qmask[(size_t)b * SS + q0 + ql];
        float inv = (l1 > 0.f && qm != 0.f) ? 1.f / l1 : 0.f;
        u16* orow = att + ((size_t)b * SS + q0 + ql) * 1024 + h * 64;
#pragma unroll
        for (int c = 0; c < 4; ++c)
#pragma unroll
            for (int pp = 0; pp < 2; ++pp) {
                int d0 = 8 * c + 4 * hi + 2 * pp;
                u32 w0 = cvt_pk_bf16(acc0[4 * c + 2 * pp] * inv, acc0[4 * c + 2 * pp + 1] * inv);
                u32 w1 = cvt_pk_bf16(acc1[4 * c + 2 * pp] * inv, acc1[4 * c + 2 * pp + 1] * inv);
                *reinterpret_cast<u32*>(orow + d0) = w0;
                *reinterpret_cast<u32*>(orow + 32 + d0) = w1;
            }
    }
}

// ---------------- K3: final GEMM — 512 threads (8 waves), counted-vmcnt depth-2 pipeline ----------------
__global__ __launch_bounds__(512, 2) void gemm_final_kernel(
    const u16* __restrict__ A, const u16* __restrict__ BT,
    const float* __restrict__ b2, float* __restrict__ out)
{
    const int id = blockIdx.x;
    const int xcd = id & 7, idx = id >> 3;       // idx 0..31
    const int p = xcd * 4 + (idx >> 3);          // m-panel 0..31
    const int m0 = p * 128;
    const int n0 = (idx & 7) * 128;

    __shared__ u16 a_lds[3][128][64];
    __shared__ u16 b_lds[3][128][64];

    const int tid = threadIdx.x;
    const int lane = tid & 63;
    const int w = tid >> 6;              // 8 waves
    const int wm = w >> 1, wn = w & 1;   // wave tile: 32 rows x 64 cols
    const int lrow = lane & 15;
    const int lgrp = lane >> 4;

    f32x4 acc[2][4] = {};

#define STAGEF(bufi, k0s)                                                                  \
    do {                                                                                   \
        _Pragma("unroll")                                                                  \
        for (int it = 0; it < 2; ++it) {                                                   \
            int s_ = tid + it * 512;                                                       \
            int row_ = s_ >> 3;                                                            \
            int sc_ = ((((s_ & 7) * 16) ^ ((row_ & 7) << 4)) >> 1);                        \
            gl_lds16(&A[(size_t)(m0 + row_) * 1024 + (k0s) + sc_], &a_lds[bufi][0][0] + s_ * 8);  \
            gl_lds16(&BT[(size_t)(n0 + row_) * 1024 + (k0s) + sc_], &b_lds[bufi][0][0] + s_ * 8); \
        }                                                                                  \
    } while (0)

#define COMPUTEF(bufi)                                                                     \
    do {                                                                                   \
        const char* ab_ = reinterpret_cast<const char*>(&a_lds[bufi][0][0]);               \
        const char* bb_ = reinterpret_cast<const char*>(&b_lds[bufi][0][0]);               \
        _Pragma("unroll")                                                                  \
        for (int kk = 0; kk < 2; ++kk) {                                                   \
            bf16x8 af[2], bfr[4];                                                          \
            _Pragma("unroll")                                                              \
            for (int i = 0; i < 2; ++i) {                                                  \
                int row = wm * 32 + i * 16 + lrow;                                         \
                af[i] = *reinterpret_cast<const bf16x8*>(ab_ + row * 128 + ((kk * 64 + lgrp * 16) ^ ((row & 7) << 4))); \
            }                                                                              \
            _Pragma("unroll")                                                              \
            for (int j = 0; j < 4; ++j) {                                                  \
                int row = wn * 64 + j * 16 + lrow;                                         \
                bfr[j] = *reinterpret_cast<const bf16x8*>(bb_ + row * 128 + ((kk * 64 + lgrp * 16) ^ ((row & 7) << 4))); \
            }                                                                              \
            _Pragma("unroll")                                                              \
            for (int i = 0; i < 2; ++i)                                                    \
                _Pragma("unroll")                                                          \
                for (int j = 0; j < 4; ++j)                                                \
                    acc[i][j] = __builtin_amdgcn_mfma_f32_16x16x32_bf16(af[i], bfr[j], acc[i][j], 0, 0, 0); \
        }                                                                                  \
    } while (0)

    STAGEF(0, 0);
    STAGEF(1, 64);
    asm volatile("s_waitcnt vmcnt(4)" ::: "memory");
    __builtin_amdgcn_s_barrier();

#pragma unroll
    for (int t = 0; t < 16; ++t) {
        if (t < 14) STAGEF((t + 2) % 3, (t + 2) * 64);

        COMPUTEF(t % 3);

        if (t < 14)       asm volatile("s_waitcnt vmcnt(4)" ::: "memory");
        else if (t == 14) asm volatile("s_waitcnt vmcnt(0)" ::: "memory");
        if (t < 15) __builtin_amdgcn_s_barrier();
    }
#undef STAGEF
#undef COMPUTEF

#pragma unroll
    for (int i = 0; i < 2; ++i) {
#pragma unroll
        for (int j = 0; j < 4; ++j) {
            int n = n0 + wn * 64 + j * 16 + lrow;
            float bb = b2[n];
#pragma unroll
            for (int r = 0; r < 4; ++r) {
                int m = m0 + wm * 32 + i * 16 + lgrp * 4 + r;
                out[(size_t)m * 1024 + n] = acc[i][j][r] + bb;
            }
        }
    }
}

extern "C" void kernel_launch(void* const* d_in, const int* in_sizes, int n_in,
                              void* d_out, int out_size, void* d_ws, size_t ws_size,
                              hipStream_t stream) {
    const float* query = (const float*)d_in[0];
    const float* key   = (const float*)d_in[1];
    const float* value = (const float*)d_in[2];
    const float* qmask = (const float*)d_in[3];
    const float* kmask = (const float*)d_in[4];
    const float* Wq = (const float*)d_in[5];
    const float* bq = (const float*)d_in[6];
    const float* Wk = (const float*)d_in[7];
    const float* bk = (const float*)d_in[8];
    const float* Wv = (const float*)d_in[9];
    const float* bv = (const float*)d_in[10];
    const float* Wo = (const float*)d_in[11];
    const float* bo = (const float*)d_in[12];
    const float* Wf = (const float*)d_in[13];
    const float* bfin = (const float*)d_in[14];
    float* out = (float*)d_out;

    char* ws = (char*)d_ws;
    u16*   WT  = (u16*)  (ws + 0);          // 6291456
    u16*   W2T = (u16*)  (ws + 6291456);    // 2097152
    float* b2  = (float*)(ws + 8388608);    // 4096
    u16*   qbf = (u16*)  (ws + 8392704);    // 8388608
    u16*   kbf = (u16*)  (ws + 16781312);   // 8388608
    u16*   att = (u16*)  (ws + 25169920);   // 8388608
    u16*   vtg = (u16*)  (ws + 33558528);   // 8388608  (end ~42 MB)

    hipMemsetAsync(b2, 0, 1024 * sizeof(float), stream);
    prep_kernel<<<dim3(1024), 256, 0, stream>>>(Wq, Wk, Wv, Wo, bo, Wf, bfin, WT, W2T, b2);
    gemm_qkv_kernel<<<dim3(768), 512, 0, stream>>>(query, key, value, WT, bq, bk, bv, qbf, kbf, vtg);
    attn_kernel<<<dim3(512), 512, 0, stream>>>(qbf, kbf, vtg, kmask, qmask, att);
    gemm_final_kernel<<<dim3(256), 512, 0, stream>>>(att, W2T, b2, out);
}